// Round 9
// baseline (227.266 us; speedup 1.0000x reference)
//
#include <hip/hip_runtime.h>
#include <hip/hip_bf16.h>

typedef __attribute__((ext_vector_type(8))) short short8;   // 8 bf16 = 4 VGPRs (MFMA A/B frag)
typedef __attribute__((ext_vector_type(4))) float floatx4;  // MFMA C/D frag

#define LQ 2048
#define DM 1024
#define NH 16
#define LOG2E 1.44269504088896f

typedef __attribute__((address_space(1))) void gas_t;
typedef __attribute__((address_space(3))) void las_t;

// async global->LDS, 16B per lane; LDS dest = wave-uniform base + lane*16
__device__ __forceinline__ void async16(const __hip_bfloat16* g, __hip_bfloat16* l) {
    __builtin_amdgcn_global_load_lds((gas_t*)g, (las_t*)l, 16, 0, 0);
}

// ---------------------------------------------------------------------------
// Fused prep: blocks [0,2048) convert x; [2048,4096) convert y;
// [4096,5120) transpose-convert the 4 weight matrices (64x64 tiles).
// ---------------------------------------------------------------------------
__global__ __launch_bounds__(256) void prep_all(
    const float* __restrict__ x,  const float* __restrict__ y,
    const float* __restrict__ Wq, const float* __restrict__ Wk,
    const float* __restrict__ Wv, const float* __restrict__ Wo,
    __hip_bfloat16* __restrict__ xb,  __hip_bfloat16* __restrict__ yb,
    __hip_bfloat16* __restrict__ Wqt, __hip_bfloat16* __restrict__ Wkt,
    __hip_bfloat16* __restrict__ Wvt, __hip_bfloat16* __restrict__ Wot)
{
    __shared__ float tile[64][65];
    const int t  = threadIdx.x;
    const int bx = blockIdx.x;

    if (bx < 4096) {
        const float* in = (bx < 2048) ? x : y;
        __hip_bfloat16* out = (bx < 2048) ? xb : yb;
        const int i = ((bx & 2047) * 256 + t) * 8;
        float4 a0 = ((const float4*)(in + i))[0];
        float4 a1 = ((const float4*)(in + i))[1];
        union { __hip_bfloat16 h[8]; uint4 u; } pk;
        pk.h[0] = __float2bfloat16(a0.x); pk.h[1] = __float2bfloat16(a0.y);
        pk.h[2] = __float2bfloat16(a0.z); pk.h[3] = __float2bfloat16(a0.w);
        pk.h[4] = __float2bfloat16(a1.x); pk.h[5] = __float2bfloat16(a1.y);
        pk.h[6] = __float2bfloat16(a1.z); pk.h[7] = __float2bfloat16(a1.w);
        *(uint4*)(out + i) = pk.u;
        return;
    }

    const int r    = bx - 4096;       // 0..1023
    const int wsel = r >> 8;          // 0..3
    const int tid  = r & 255;
    const int n0   = (tid & 15) * 64, k0 = (tid >> 4) * 64;
    const float* W = (wsel == 0) ? Wq : (wsel == 1) ? Wk : (wsel == 2) ? Wv : Wo;
    __hip_bfloat16* Wt = (wsel == 0) ? Wqt : (wsel == 1) ? Wkt : (wsel == 2) ? Wvt : Wot;

    const int rr0 = t >> 4, c4 = (t & 15) * 4;
#pragma unroll
    for (int rr = 0; rr < 64; rr += 16) {
        float4 v = *(const float4*)&W[(size_t)(k0 + rr0 + rr) * DM + n0 + c4];
        tile[rr0 + rr][c4 + 0] = v.x; tile[rr0 + rr][c4 + 1] = v.y;
        tile[rr0 + rr][c4 + 2] = v.z; tile[rr0 + rr][c4 + 3] = v.w;
    }
    __syncthreads();
    const int nr = t >> 2, kc = (t & 3) * 16;
    union { __hip_bfloat16 h[16]; uint4 u[2]; } pk;
#pragma unroll
    for (int i = 0; i < 16; ++i) pk.h[i] = __float2bfloat16(tile[kc + i][nr]);
    uint4* dst = (uint4*)&Wt[(size_t)(n0 + nr) * DM + k0 + kc];
    dst[0] = pk.u[0];
    dst[1] = pk.u[1];
}

// ---------------------------------------------------------------------------
// Fused QKV GEMM v3: 256x256 tile, 512 threads = 8 waves (2M x 4N), each wave
// owns a 128x64 output (M_rep=8, N_rep=4). Round-7-proven 3-buffer depth-2
// counted-vmcnt skeleton (4 async16/thread/stage -> vmcnt(4)/vmcnt(0),
// race-safe post-barrier staging). MFMA:ds_read density 32:12 per wave-iter
// vs 16:8 at 128^2 -- half the barriers per FLOP.
// Grid 192 = 8 XCD x (6bx x 4by); ~5MB/XCD working set.
// n in [0,1024)   -> Q = x*Wq + bq, scaled, row-major bf16
// n in [1024,2048)-> K = y*Wk + bk, row-major bf16
// n in [2048,3072)-> V = y*Wv + bv, TRANSPOSED per head: Vt[b][h][d][j]
// ---------------------------------------------------------------------------
__global__ __launch_bounds__(512) void gemm_qkv(
    const __hip_bfloat16* __restrict__ xb,
    const __hip_bfloat16* __restrict__ yb,
    const __hip_bfloat16* __restrict__ Bt,   // Wqt (Wkt, Wvt contiguous after)
    const float* __restrict__ bq, const float* __restrict__ bk,
    const float* __restrict__ bv,
    __hip_bfloat16* __restrict__ Qb, __hip_bfloat16* __restrict__ Kb,
    __hip_bfloat16* __restrict__ Vt,
    float qscl)
{
    constexpr int BM = 256, BN = 256, BK = 32, Kd = 1024, NIT = Kd / BK;
    __shared__ __align__(16) __hip_bfloat16 As[3][BM * BK];  // 3 x 16 KB
    __shared__ __align__(16) __hip_bfloat16 Bs[3][BN * BK];  // 3 x 16 KB

    const int t    = threadIdx.x;
    const int w    = t >> 6;        // 0..7
    const int lane = t & 63;
    const int quad = lane >> 4;
    const int l16  = lane & 15;
    const int wm   = w & 1;         // 2 m-halves of 128 rows
    const int wn   = w >> 1;        // 4 n-quarters of 64 cols

    // XCD-rect decode: 192 = 8 XCD x (6bx x 4by); n-tiles 12, m-tiles 16
    const int f  = blockIdx.x;
    const int rx = f & 7;
    const int rr = f >> 3;               // 0..23
    const int bx = (rx & 1) * 6 + rr % 6;
    const int by = (rx >> 1) * 4 + rr / 6;
    const int m0 = by * BM;
    const int n0 = bx * BN;

    const int region = n0 >> 10;             // 0=Q 1=K 2=V (block-uniform, 1024%256==0)
    const int nl     = n0 & 1023;

    const __hip_bfloat16* A = (region == 0) ? xb : yb;

    const int lrow = lane >> 2;          // 16 rows per segment
    const int lcol = (lane & 3) * 8;     // 4 x 8 bf16 = 32 cols

    floatx4 acc[8][4];
#pragma unroll
    for (int i = 0; i < 8; ++i)
#pragma unroll
        for (int j = 0; j < 4; ++j) acc[i][j] = (floatx4){0.f, 0.f, 0.f, 0.f};

    // A: 16 segs of 16 rows; B: 16 segs. 8 waves x 2 segs each => 4 async16/thr.
    auto stage = [&](int k0, int buf) {
#pragma unroll
        for (int s = 0; s < 2; ++s) {
            const int seg = w * 2 + s;
            async16(A + (size_t)(m0 + seg * 16 + lrow) * Kd + k0 + lcol,
                    &As[buf][seg * 16 * BK]);
            async16(Bt + (size_t)(n0 + seg * 16 + lrow) * Kd + k0 + lcol,
                    &Bs[buf][seg * 16 * BK]);
        }
    };

    stage(0, 0);
    stage(BK, 1);
    int cur = 0;
    for (int i = 0; i < NIT; ++i) {
        // retire own stage(i) (4 loads), leave stage(i+1) in flight
        if (i < NIT - 1) asm volatile("s_waitcnt vmcnt(4)" ::: "memory");
        else             asm volatile("s_waitcnt vmcnt(0)" ::: "memory");
        __builtin_amdgcn_sched_barrier(0);
        __builtin_amdgcn_s_barrier();
        // safe: buffer (cur+2)%3 was retired by the barrier above
        if (i + 2 < NIT) stage((i + 2) * BK, (cur + 2 >= 3) ? cur - 1 : cur + 2);

        short8 af[8], bf[4];
#pragma unroll
        for (int mi = 0; mi < 8; ++mi)
            af[mi] = *(const short8*)&As[cur][(wm * 128 + mi * 16 + l16) * BK + quad * 8];
#pragma unroll
        for (int j = 0; j < 4; ++j)
            bf[j] = *(const short8*)&Bs[cur][(wn * 64 + j * 16 + l16) * BK + quad * 8];
#pragma unroll
        for (int mi = 0; mi < 8; ++mi)
#pragma unroll
            for (int j = 0; j < 4; ++j)
                acc[mi][j] = __builtin_amdgcn_mfma_f32_16x16x32_bf16(af[mi], bf[j], acc[mi][j], 0, 0, 0);
        cur = (cur + 1 >= 3) ? 0 : cur + 1;
    }

    if (region < 2) {
        __hip_bfloat16* C    = (region == 0) ? Qb : Kb;
        const float*    bias = (region == 0) ? bq : bk;
        const float     scl  = (region == 0) ? qscl : 1.0f;
#pragma unroll
        for (int j = 0; j < 4; ++j) {
            const int col = nl + wn * 64 + j * 16 + l16;
            const float bvv = bias[col];
#pragma unroll
            for (int mi = 0; mi < 8; ++mi) {
#pragma unroll
                for (int r = 0; r < 4; ++r) {
                    const int row = m0 + wm * 128 + mi * 16 + quad * 4 + r;
                    C[(size_t)row * 1024 + col] = __float2bfloat16((acc[mi][j][r] + bvv) * scl);
                }
            }
        }
    } else {
        // V transposed per head: addr = (b*1024 + col)*2048 + j.
#pragma unroll
        for (int j = 0; j < 4; ++j) {
            const int col = nl + wn * 64 + j * 16 + l16;
            const float bvv = bv[col];
#pragma unroll
            for (int mi = 0; mi < 8; ++mi) {
                const int row0 = m0 + wm * 128 + mi * 16 + quad * 4;
                union { __hip_bfloat16 h4[4]; uint2 u; } pk;
#pragma unroll
                for (int r = 0; r < 4; ++r)
                    pk.h4[r] = __float2bfloat16(acc[mi][j][r] + bvv);
                *(uint2*)&Vt[((size_t)((row0 >> 11) * 1024 + col)) * 2048 + (row0 & 2047)] = pk.u;
            }
        }
    }
}

// ---------------------------------------------------------------------------
// O-projection GEMM: 64x128 tile, XCD-rect, f32 out; 3-buffer depth-2
// counted-vmcnt pipeline (3 async16/stage -> vmcnt(3|0)).
// ---------------------------------------------------------------------------
__global__ __launch_bounds__(256) void gemm_o(
    const __hip_bfloat16* __restrict__ A,    // [M,1024]
    const __hip_bfloat16* __restrict__ Bt,   // [1024,1024] (Wot)
    const float* __restrict__ bias,
    float* __restrict__ C,                   // [M,1024] f32
    int M)
{
    constexpr int BM = 64, BN = 128, BK = 32, Kd = 1024, NIT = Kd / BK;
    __shared__ __align__(16) __hip_bfloat16 As[3][BM * BK];  // 3 x 4 KB
    __shared__ __align__(16) __hip_bfloat16 Bs[3][BN * BK];  // 3 x 8 KB

    const int t    = threadIdx.x;
    const int w    = t >> 6;
    const int lane = t & 63;
    const int quad = lane >> 4;
    const int l16  = lane & 15;
    const int wm   = w & 1;         // 2 m-halves of 32 rows
    const int wn   = w >> 1;        // 2 n-halves of 64 cols

    // XCD-rect decode: 512 = 8 XCD x (4bx x 16by)
    const int f  = blockIdx.x;
    const int rx = f & 7;
    const int rr = f >> 3;               // 0..63
    const int bx = (rx & 1) * 4 + (rr & 3);
    const int by = (rx >> 1) * 16 + (rr >> 2);
    const int m0 = by * BM;
    const int n0 = bx * BN;

    const int lrow = lane >> 2;
    const int lcol = (lane & 3) * 8;

    floatx4 acc[2][4];
#pragma unroll
    for (int i = 0; i < 2; ++i)
#pragma unroll
        for (int j = 0; j < 4; ++j) acc[i][j] = (floatx4){0.f, 0.f, 0.f, 0.f};

    // 12 segments (4 A + 8 B), 3 per wave
    auto stage = [&](int k0, int buf) {
#pragma unroll
        for (int s = 0; s < 3; ++s) {
            const int seg = w * 3 + s;
            if (seg < 4) {
                async16(A + (size_t)(m0 + seg * 16 + lrow) * Kd + k0 + lcol,
                        &As[buf][seg * 16 * BK]);
            } else {
                const int bs = seg - 4;
                async16(Bt + (size_t)(n0 + bs * 16 + lrow) * Kd + k0 + lcol,
                        &Bs[buf][bs * 16 * BK]);
            }
        }
    };

    stage(0, 0);
    stage(BK, 1);
    int cur = 0;
    for (int i = 0; i < NIT; ++i) {
        if (i < NIT - 1) asm volatile("s_waitcnt vmcnt(3)" ::: "memory");
        else             asm volatile("s_waitcnt vmcnt(0)" ::: "memory");
        __builtin_amdgcn_sched_barrier(0);
        __builtin_amdgcn_s_barrier();
        if (i + 2 < NIT) stage((i + 2) * BK, (cur + 2 >= 3) ? cur - 1 : cur + 2);

        short8 af[2], bf[4];
#pragma unroll
        for (int ii = 0; ii < 2; ++ii)
            af[ii] = *(const short8*)&As[cur][(wm * 32 + ii * 16 + l16) * BK + quad * 8];
#pragma unroll
        for (int j = 0; j < 4; ++j)
            bf[j] = *(const short8*)&Bs[cur][(wn * 64 + j * 16 + l16) * BK + quad * 8];
#pragma unroll
        for (int ii = 0; ii < 2; ++ii)
#pragma unroll
            for (int j = 0; j < 4; ++j)
                acc[ii][j] = __builtin_amdgcn_mfma_f32_16x16x32_bf16(af[ii], bf[j], acc[ii][j], 0, 0, 0);
        cur = (cur + 1 >= 3) ? 0 : cur + 1;
    }

#pragma unroll
    for (int j = 0; j < 4; ++j) {
        const int col = n0 + wn * 64 + j * 16 + l16;
        const float bvf = bias[col];
#pragma unroll
        for (int i = 0; i < 2; ++i) {
#pragma unroll
            for (int r = 0; r < 4; ++r) {
                const int row = m0 + wm * 32 + i * 16 + quad * 4 + r;
                C[(size_t)row * 1024 + col] = acc[i][j][r] + bvf;
            }
        }
    }
}

// ---------------------------------------------------------------------------
// Fallback GEMM (fp32 inputs, fused convert, 64x64 tile). TRANSV writes the
// output per-head-transposed into Vt layout.
// ---------------------------------------------------------------------------
template <bool A_IS_F32, bool OUT_F32, bool TRANSV = false>
__global__ __launch_bounds__(256) void gemm64(
    const void* __restrict__ Av,
    const float* __restrict__ B,
    const float* __restrict__ bias,
    void* __restrict__ Cv,
    int M, int N, int K, float scale)
{
    __shared__ __align__(16) __hip_bfloat16 As[64][40];
    __shared__ __align__(16) __hip_bfloat16 Bs[64][40];

    const int t    = threadIdx.x;
    const int wave = t >> 6;
    const int lane = t & 63;
    const int quad = lane >> 4;
    const int l16  = lane & 15;
    const int m0   = blockIdx.y * 64;
    const int n0   = blockIdx.x * 64;

    floatx4 acc[4];
#pragma unroll
    for (int i = 0; i < 4; ++i) acc[i] = (floatx4){0.f, 0.f, 0.f, 0.f};

    const int arow = t >> 2, acol = (t & 3) * 8;
    const int bkk  = t >> 3, bnn  = (t & 7) * 8;

    for (int k0 = 0; k0 < K; k0 += 32) {
        if constexpr (A_IS_F32) {
            const float* A = (const float*)Av;
            const float* ap = A + (size_t)(m0 + arow) * K + k0 + acol;
            float4 a0 = ((const float4*)ap)[0];
            float4 a1 = ((const float4*)ap)[1];
            union { __hip_bfloat16 h[8]; short8 s; } up;
            up.h[0] = __float2bfloat16(a0.x); up.h[1] = __float2bfloat16(a0.y);
            up.h[2] = __float2bfloat16(a0.z); up.h[3] = __float2bfloat16(a0.w);
            up.h[4] = __float2bfloat16(a1.x); up.h[5] = __float2bfloat16(a1.y);
            up.h[6] = __float2bfloat16(a1.z); up.h[7] = __float2bfloat16(a1.w);
            *(short8*)(&As[arow][acol]) = up.s;
        } else {
            const __hip_bfloat16* A = (const __hip_bfloat16*)Av;
            uint4 av = *(const uint4*)(A + (size_t)(m0 + arow) * K + k0 + acol);
            *(uint4*)(&As[arow][acol]) = av;
        }
        {
            const float* bp = B + (size_t)(k0 + bkk) * N + n0 + bnn;
            float4 b0 = ((const float4*)bp)[0];
            float4 b1 = ((const float4*)bp)[1];
            Bs[bnn + 0][bkk] = __float2bfloat16(b0.x);
            Bs[bnn + 1][bkk] = __float2bfloat16(b0.y);
            Bs[bnn + 2][bkk] = __float2bfloat16(b0.z);
            Bs[bnn + 3][bkk] = __float2bfloat16(b0.w);
            Bs[bnn + 4][bkk] = __float2bfloat16(b1.x);
            Bs[bnn + 5][bkk] = __float2bfloat16(b1.y);
            Bs[bnn + 6][bkk] = __float2bfloat16(b1.z);
            Bs[bnn + 7][bkk] = __float2bfloat16(b1.w);
        }
        __syncthreads();

        short8 afrag = *(const short8*)(&As[wave * 16 + l16][quad * 8]);
#pragma unroll
        for (int nt = 0; nt < 4; ++nt) {
            short8 bfrag = *(const short8*)(&Bs[nt * 16 + l16][quad * 8]);
            acc[nt] = __builtin_amdgcn_mfma_f32_16x16x32_bf16(afrag, bfrag, acc[nt], 0, 0, 0);
        }
        __syncthreads();
    }

#pragma unroll
    for (int nt = 0; nt < 4; ++nt) {
        const int col = n0 + nt * 16 + l16;
        const float bvf = bias[col];
        if constexpr (TRANSV) {
            const int row0 = m0 + wave * 16 + quad * 4;
            union { __hip_bfloat16 h4[4]; uint2 u; } pk;
#pragma unroll
            for (int r = 0; r < 4; ++r)
                pk.h4[r] = __float2bfloat16(acc[nt][r] + bvf);
            *(uint2*)&((__hip_bfloat16*)Cv)[((size_t)((row0 >> 11) * 1024 + col)) * 2048 + (row0 & 2047)] = pk.u;
        } else {
#pragma unroll
            for (int r = 0; r < 4; ++r) {
                const int row = m0 + wave * 16 + quad * 4 + r;
                const float v = (acc[nt][r] + bvf) * scale;
                if constexpr (OUT_F32) ((float*)Cv)[(size_t)row * N + col] = v;
                else ((__hip_bfloat16*)Cv)[(size_t)row * N + col] = __float2bfloat16(v);
            }
        }
    }
}

// ---------------------------------------------------------------------------
// MFMA flash attention v10 (round-7 proven, unchanged): XCD-clustered +
// causal balance pairing (34 iters/CU), 3-buffer depth-2 counted vmcnt,
// race-safe post-barrier staging, setprio around PV.
// ---------------------------------------------------------------------------
#define PP 72                 // P/Q row pitch (144 B = 9*16B, aligned)

__global__ __launch_bounds__(256, 2) void attn_mfma10(
    const __hip_bfloat16* __restrict__ Q,
    const __hip_bfloat16* __restrict__ K,
    const __hip_bfloat16* __restrict__ Vt,   // [b][h][64 d][2048 j]
    __hip_bfloat16* __restrict__ O)
{
    __shared__ __align__(16) __hip_bfloat16 KtS[3][64 * 64];  // 3 x 8 KB, swizzled rows
    __shared__ __align__(16) __hip_bfloat16 VtS[3][64 * 64];  // 3 x 8 KB, swizzled rows
    __shared__ __align__(16) __hip_bfloat16 PsQ[128 * PP];    // 18 KB: Q stage, then per-wave P

    const int t    = threadIdx.x;
    const int w    = t >> 6;
    const int lane = t & 63;
    const int quad = lane >> 4;
    const int l16  = lane & 15;

    // XCD-clustered + balance-paired decode
    const int f   = blockIdx.x;
    const int xcd = f & 7;
    const int u   = f >> 3;        // 0..63
    const int pi  = u >> 4;        // 0..3 (pair index within XCD)
    const int qr  = u & 15;
    const int qx  = (pi & 2) ? (15 - qr) : qr;   // second round flips -> 34 iters/CU
    const int p   = xcd * 4 + pi;  // (b,h) pair 0..31
    const int h   = p & 15;
    const int b   = p >> 4;
    const int q0  = qx * 128;

    const size_t rowbase = (size_t)b * LQ;
    const int    hcol    = h * 64;
    const size_t vbase   = (size_t)(b * NH + h) * 64 * LQ;

    const int r8 = l16 & 7;

    // stage K and V^T 64x64 tiles; LDS linear dest, source chunk-swizzled so
    // that swizzled reads (chunk ^ row&7) return logical data. 4 async16/thr.
    auto stage = [&](int j0n, int buf) {
#pragma unroll
        for (int rnd = 0; rnd < 2; ++rnd) {
            const int c   = rnd * 256 + t;          // 16B chunk index, 0..511
            const int row = c >> 3;                 // 0..63
            const int ch  = (c & 7) ^ (row & 7);    // swizzled source chunk
            async16(K + (rowbase + j0n + row) * DM + hcol + ch * 8,
                    &KtS[buf][c * 8]);
            async16(Vt + vbase + (size_t)row * LQ + j0n + ch * 8,
                    &VtS[buf][c * 8]);
        }
    };

    // ---- Q tile (128 rows x 64) -> LDS (wave-local rows: no barrier) ----
    {
        const int qrow = t >> 1, qseg = (t & 1) * 32;   // 64B per thread
        const uint4* src = (const uint4*)(Q + (rowbase + q0 + qrow) * DM + hcol + qseg);
        uint4* dst = (uint4*)&PsQ[qrow * PP + qseg];
        dst[0] = src[0]; dst[1] = src[1]; dst[2] = src[2]; dst[3] = src[3];
    }
    stage(0, 0);
    stage(64, 1);

    // qf reads own wave's rows (ordered vs own stores by lgkmcnt)
    short8 qf[2][2];
#pragma unroll
    for (int g = 0; g < 2; ++g)
#pragma unroll
        for (int hh = 0; hh < 2; ++hh)
            qf[g][hh] = *(const short8*)&PsQ[(w * 32 + g * 16 + l16) * PP + hh * 32 + quad * 8];

    __hip_bfloat16* Pw = &PsQ[(w * 32) * PP];  // wave-private P[32 q][64 j]

    float l_i[2] = {0.f, 0.f};
    floatx4 o[2][4];
#pragma unroll
    for (int g = 0; g < 2; ++g)
#pragma unroll
        for (int i = 0; i < 4; ++i) o[g][i] = (floatx4){0.f, 0.f, 0.f, 0.f};

    const int wq_lo  = q0 + w * 32;       // first q row of this wave
    const int wq_hi  = wq_lo + 31;
    const int ntiles = 2 * qx + 2;

    int cur = 0;
    for (int jt = 0; jt < ntiles; ++jt) {
        const int j0 = jt * 64;

        // retire own stage(jt) (4 loads), keep stage(jt+1) in flight
        if (jt < ntiles - 1) asm volatile("s_waitcnt vmcnt(4)" ::: "memory");
        else                 asm volatile("s_waitcnt vmcnt(0)" ::: "memory");
        __builtin_amdgcn_sched_barrier(0);
        __builtin_amdgcn_s_barrier();
        // safe: buffer (cur+2)%3 was retired by the barrier above
        if (jt + 2 < ntiles) stage(j0 + 128, (cur + 2 >= 3) ? cur - 1 : cur + 2);

        if (j0 <= wq_hi) {
            const bool bnd = (j0 + 63 > wq_lo);   // boundary: needs causal mask
            // ---- S^T = K * Q^T, fused softmax numerator per (g, jc) ----
#pragma unroll
            for (int jc = 0; jc < 4; ++jc) {
                const __hip_bfloat16* kr = &KtS[cur][(jc * 16 + l16) * 64];
                short8 ak0 = *(const short8*)&kr[((quad    ) ^ r8) * 8];
                short8 ak1 = *(const short8*)&kr[((quad + 4) ^ r8) * 8];
#pragma unroll
                for (int g = 0; g < 2; ++g) {
                    floatx4 z = (floatx4){0.f, 0.f, 0.f, 0.f};
                    z = __builtin_amdgcn_mfma_f32_16x16x32_bf16(ak0, qf[g][0], z, 0, 0, 0);
                    z = __builtin_amdgcn_mfma_f32_16x16x32_bf16(ak1, qf[g][1], z, 0, 0, 0);
                    if (bnd) {
                        const int qg = wq_lo + g * 16 + l16;
#pragma unroll
                        for (int r = 0; r < 4; ++r) {
                            const int j = j0 + jc * 16 + quad * 4 + r;
                            if (j > qg) z[r] = -1e30f;
                        }
                    }
                    union { __hip_bfloat16 h4[4]; uint2 u; } pk;
#pragma unroll
                    for (int r = 0; r < 4; ++r) {
                        const float e = __builtin_amdgcn_exp2f(z[r]);
                        l_i[g] += e;
                        pk.h4[r] = __float2bfloat16(e);
                    }
                    *(uint2*)&Pw[(g * 16 + l16) * PP + jc * 16 + quad * 4] = pk.u;
                }
            }
            // ---- P frags (wave-local write->read) ----
            short8 pa[2][2];
#pragma unroll
            for (int g = 0; g < 2; ++g) {
                pa[g][0] = *(const short8*)&Pw[(g * 16 + l16) * PP + quad * 8];
                pa[g][1] = *(const short8*)&Pw[(g * 16 + l16) * PP + 32 + quad * 8];
            }
            // ---- O += P * V (pure-MFMA cluster: setprio) ----
            __builtin_amdgcn_s_setprio(1);
#pragma unroll
            for (int subf = 0; subf < 4; ++subf) {
                const __hip_bfloat16* vr = &VtS[cur][(subf * 16 + l16) * 64];
                short8 vb0 = *(const short8*)&vr[((quad    ) ^ r8) * 8];
                short8 vb1 = *(const short8*)&vr[((quad + 4) ^ r8) * 8];
#pragma unroll
                for (int g = 0; g < 2; ++g) {
                    o[g][subf] = __builtin_amdgcn_mfma_f32_16x16x32_bf16(pa[g][0], vb0, o[g][subf], 0, 0, 0);
                    o[g][subf] = __builtin_amdgcn_mfma_f32_16x16x32_bf16(pa[g][1], vb1, o[g][subf], 0, 0, 0);
                }
            }
            __builtin_amdgcn_s_setprio(0);
        }
        cur = (cur + 1 >= 3) ? 0 : cur + 1;
    }

#pragma unroll
    for (int g = 0; g < 2; ++g) {
        l_i[g] += __shfl_xor(l_i[g], 16);
        l_i[g] += __shfl_xor(l_i[g], 32);
#pragma unroll
        for (int r = 0; r < 4; ++r) {
            const float linv = 1.0f / __shfl(l_i[g], quad * 4 + r);
            const size_t row = rowbase + q0 + w * 32 + g * 16 + quad * 4 + r;
#pragma unroll
            for (int subf = 0; subf < 4; ++subf)
                O[row * DM + hcol + subf * 16 + l16] = __float2bfloat16(o[g][subf][r] * linv);
        }
    }
}

// ---------------------------------------------------------------------------
extern "C" void kernel_launch(void* const* d_in, const int* in_sizes, int n_in,
                              void* d_out, int out_size, void* d_ws, size_t ws_size,
                              hipStream_t stream)
{
    (void)in_sizes; (void)n_in; (void)out_size;

    const float* x  = (const float*)d_in[0];
    const float* y  = (const float*)d_in[1];
    // d_in[2] = mask: causal tril, handled analytically
    const float* Wq = (const float*)d_in[3];
    const float* bq = (const float*)d_in[4];
    const float* Wk = (const float*)d_in[5];
    const float* bk = (const float*)d_in[6];
    const float* Wv = (const float*)d_in[7];
    const float* bv = (const float*)d_in[8];
    const float* Wo = (const float*)d_in[9];
    const float* bo = (const float*)d_in[10];

    const size_t NTOK = (size_t)2 * LQ * DM;   // 4,194,304
    const size_t MM   = (size_t)DM * DM;       // 1,048,576
    const int    M    = 2 * LQ;                // 4096
    const float  QSCL = 0.125f * LOG2E;        // 1/sqrt(dk) * log2(e): exp2-domain softmax

    __hip_bfloat16* Qb  = (__hip_bfloat16*)d_ws;
    __hip_bfloat16* Kb  = Qb + NTOK;
    __hip_bfloat16* Vtb = Kb + NTOK;           // transposed V: [b][h][64][2048]
    __hip_bfloat16* Ab  = Vtb + NTOK;

    const size_t need = (4 * NTOK + 2 * NTOK + 4 * MM) * sizeof(__hip_bfloat16);
    const dim3 agrid(512, 1, 1);  // flat, XCD-clustered decode in-kernel

    if (ws_size >= need) {
        __hip_bfloat16* xb  = Ab + NTOK;
        __hip_bfloat16* yb  = xb + NTOK;
        __hip_bfloat16* Wqt = yb + NTOK;
        __hip_bfloat16* Wkt = Wqt + MM;   // [Wqt; Wkt; Wvt] contiguous = stacked QKV B
        __hip_bfloat16* Wvt = Wkt + MM;
        __hip_bfloat16* Wot = Wvt + MM;
        (void)Wkt; (void)Wvt;

        prep_all<<<5120, 256, 0, stream>>>(x, y, Wq, Wk, Wv, Wo,
                                           xb, yb, Wqt, Wkt, Wvt, Wot);

        gemm_qkv<<<192, 512, 0, stream>>>(xb, yb, Wqt, bq, bk, bv, Qb, Kb, Vtb, QSCL);
        attn_mfma10<<<agrid, 256, 0, stream>>>(Qb, Kb, Vtb, Ab);
        gemm_o<<<512, 256, 0, stream>>>(Ab, Wot, bo, (float*)d_out, M);
    } else {
        const dim3 gblk(DM / 64, M / 64);
        gemm64<true,  false><<<gblk, 256, 0, stream>>>(x, Wq, bq, Qb, M, DM, DM, QSCL);
        gemm64<true,  false><<<gblk, 256, 0, stream>>>(y, Wk, bk, Kb, M, DM, DM, 1.0f);
        gemm64<true,  false, true><<<gblk, 256, 0, stream>>>(y, Wv, bv, Vtb, M, DM, DM, 1.0f);
        attn_mfma10<<<agrid, 256, 0, stream>>>(Qb, Kb, Vtb, Ab);
        gemm64<false, true ><<<gblk, 256, 0, stream>>>(Ab, Wo, bo, (float*)d_out, M, DM, DM, 1.0f);
    }
}

// Round 10
// 216.805 us; speedup vs baseline: 1.0482x; 1.0482x over previous
//
#include <hip/hip_runtime.h>
#include <hip/hip_bf16.h>

typedef __attribute__((ext_vector_type(8))) short short8;   // 8 bf16 = 4 VGPRs (MFMA A/B frag)
typedef __attribute__((ext_vector_type(4))) float floatx4;  // MFMA C/D frag

#define LQ 2048
#define DM 1024
#define NH 16
#define LOG2E 1.44269504088896f

typedef __attribute__((address_space(1))) void gas_t;
typedef __attribute__((address_space(3))) void las_t;

// async global->LDS, 16B per lane; LDS dest = wave-uniform base + lane*16
__device__ __forceinline__ void async16(const __hip_bfloat16* g, __hip_bfloat16* l) {
    __builtin_amdgcn_global_load_lds((gas_t*)g, (las_t*)l, 16, 0, 0);
}

// ---------------------------------------------------------------------------
// Fused prep: blocks [0,2048) convert x; [2048,4096) convert y;
// [4096,5120) transpose-convert the 4 weight matrices (64x64 tiles).
// ---------------------------------------------------------------------------
__global__ __launch_bounds__(256) void prep_all(
    const float* __restrict__ x,  const float* __restrict__ y,
    const float* __restrict__ Wq, const float* __restrict__ Wk,
    const float* __restrict__ Wv, const float* __restrict__ Wo,
    __hip_bfloat16* __restrict__ xb,  __hip_bfloat16* __restrict__ yb,
    __hip_bfloat16* __restrict__ Wqt, __hip_bfloat16* __restrict__ Wkt,
    __hip_bfloat16* __restrict__ Wvt, __hip_bfloat16* __restrict__ Wot)
{
    __shared__ float tile[64][65];
    const int t  = threadIdx.x;
    const int bx = blockIdx.x;

    if (bx < 4096) {
        const float* in = (bx < 2048) ? x : y;
        __hip_bfloat16* out = (bx < 2048) ? xb : yb;
        const int i = ((bx & 2047) * 256 + t) * 8;
        float4 a0 = ((const float4*)(in + i))[0];
        float4 a1 = ((const float4*)(in + i))[1];
        union { __hip_bfloat16 h[8]; uint4 u; } pk;
        pk.h[0] = __float2bfloat16(a0.x); pk.h[1] = __float2bfloat16(a0.y);
        pk.h[2] = __float2bfloat16(a0.z); pk.h[3] = __float2bfloat16(a0.w);
        pk.h[4] = __float2bfloat16(a1.x); pk.h[5] = __float2bfloat16(a1.y);
        pk.h[6] = __float2bfloat16(a1.z); pk.h[7] = __float2bfloat16(a1.w);
        *(uint4*)(out + i) = pk.u;
        return;
    }

    const int r    = bx - 4096;       // 0..1023
    const int wsel = r >> 8;          // 0..3
    const int tid  = r & 255;
    const int n0   = (tid & 15) * 64, k0 = (tid >> 4) * 64;
    const float* W = (wsel == 0) ? Wq : (wsel == 1) ? Wk : (wsel == 2) ? Wv : Wo;
    __hip_bfloat16* Wt = (wsel == 0) ? Wqt : (wsel == 1) ? Wkt : (wsel == 2) ? Wvt : Wot;

    const int rr0 = t >> 4, c4 = (t & 15) * 4;
#pragma unroll
    for (int rr = 0; rr < 64; rr += 16) {
        float4 v = *(const float4*)&W[(size_t)(k0 + rr0 + rr) * DM + n0 + c4];
        tile[rr0 + rr][c4 + 0] = v.x; tile[rr0 + rr][c4 + 1] = v.y;
        tile[rr0 + rr][c4 + 2] = v.z; tile[rr0 + rr][c4 + 3] = v.w;
    }
    __syncthreads();
    const int nr = t >> 2, kc = (t & 3) * 16;
    union { __hip_bfloat16 h[16]; uint4 u[2]; } pk;
#pragma unroll
    for (int i = 0; i < 16; ++i) pk.h[i] = __float2bfloat16(tile[kc + i][nr]);
    uint4* dst = (uint4*)&Wt[(size_t)(n0 + nr) * DM + k0 + kc];
    dst[0] = pk.u[0];
    dst[1] = pk.u[1];
}

// ---------------------------------------------------------------------------
// Fused QKV GEMM v4: 256x256 tile, 8 waves, m201-style phase schedule.
// K processed in 32-col half-steps; LDS = 4 rotating K-half slots x
// (A 16KB + B 16KB) = 128 KB. Per half-step two phases:
//   A: ds_read bf[4]+af[0..3] | stage A(h+2) | bar | lgkm0 | prio1 16 MFMA | bar
//   B: ds_read af[4..7]       | stage B(h+2) | bar | lgkm0 | prio1 16 MFMA |
//      vmcnt(4) | bar            (counted: never drains prefetch mid-loop)
// T2 swizzle: physical 16B chunk = logical ^ ((row>>1)&3), via pre-swizzled
// global source + swizzled ds_read addr -> 2 lanes/bank (conflict-free).
// Slot h+2 overwrites slot h-2 (reads retired >=2 barriers earlier).
// Grid 192 = 8 XCD x (6bx x 4by).
// ---------------------------------------------------------------------------
__global__ __launch_bounds__(512) void gemm_qkv(
    const __hip_bfloat16* __restrict__ xb,
    const __hip_bfloat16* __restrict__ yb,
    const __hip_bfloat16* __restrict__ Bt,   // Wqt (Wkt, Wvt contiguous after)
    const float* __restrict__ bq, const float* __restrict__ bk,
    const float* __restrict__ bv,
    __hip_bfloat16* __restrict__ Qb, __hip_bfloat16* __restrict__ Kb,
    __hip_bfloat16* __restrict__ Vt,
    float qscl)
{
    constexpr int BM = 256, BN = 256, Kd = 1024;
    constexpr int NHS = Kd / 32;                 // 32 K-half steps
    __shared__ __align__(16) __hip_bfloat16 As[4][256 * 32];  // 4 x 16 KB
    __shared__ __align__(16) __hip_bfloat16 Bs[4][256 * 32];  // 4 x 16 KB

    const int t    = threadIdx.x;
    const int w    = t >> 6;        // 0..7
    const int lane = t & 63;
    const int quad = lane >> 4;
    const int l16  = lane & 15;
    const int wm   = w & 1;         // 2 m-halves of 128 rows
    const int wn   = w >> 1;        // 4 n-quarters of 64 cols

    // XCD-rect decode: 192 = 8 XCD x (6bx x 4by); n-tiles 12, m-tiles 16
    const int f  = blockIdx.x;
    const int rx = f & 7;
    const int rr = f >> 3;               // 0..23
    const int bx = (rx & 1) * 6 + rr % 6;
    const int by = (rx >> 1) * 4 + rr / 6;
    const int m0 = by * BM;
    const int n0 = bx * BN;

    const int region = n0 >> 10;             // 0=Q 1=K 2=V (block-uniform)
    const int nl     = n0 & 1023;

    const __hip_bfloat16* A = (region == 0) ? xb : yb;

    floatx4 acc[8][4];
#pragma unroll
    for (int i = 0; i < 8; ++i)
#pragma unroll
        for (int j = 0; j < 4; ++j) acc[i][j] = (floatx4){0.f, 0.f, 0.f, 0.f};

    // Stage one K-half (256 rows x 32 cols) of A or B into slot h&3.
    // 1024 chunks of 16B; thread writes chunks t and t+512 (linear LDS dest).
    // Source pre-swizzled: physical chunk c holds logical (c&3)^((row>>1)&3).
    auto stageA = [&](int h) {
        const int k0 = h * 32, slot = h & 3;
#pragma unroll
        for (int l = 0; l < 2; ++l) {
            const int c   = l * 512 + t;
            const int row = c >> 2;
            const int ch  = (c & 3) ^ ((row >> 1) & 3);
            async16(A + (size_t)(m0 + row) * Kd + k0 + ch * 8, &As[slot][c * 8]);
        }
    };
    auto stageB = [&](int h) {
        const int k0 = h * 32, slot = h & 3;
#pragma unroll
        for (int l = 0; l < 2; ++l) {
            const int c   = l * 512 + t;
            const int row = c >> 2;
            const int ch  = (c & 3) ^ ((row >> 1) & 3);
            async16(Bt + (size_t)(n0 + row) * Kd + k0 + ch * 8, &Bs[slot][c * 8]);
        }
    };

    // prologue: half-steps 0 and 1 in flight; retire 0's before first compute
    stageA(0); stageB(0); stageA(1); stageB(1);
    asm volatile("s_waitcnt vmcnt(4)" ::: "memory");
    __builtin_amdgcn_sched_barrier(0);
    __builtin_amdgcn_s_barrier();

    const int csw = (l16 >> 1) & 3;   // read-side chunk swizzle (== (row>>1)&3)

    for (int h = 0; h < NHS; ++h) {
        const int slot = h & 3;
        const __hip_bfloat16* as = &As[slot][0];
        const __hip_bfloat16* bs = &Bs[slot][0];
        short8 af[8], bf[4];

        // ---- phase A: bf[0..3] + af[0..3], stage A(h+2), 16 MFMA ----
#pragma unroll
        for (int nj = 0; nj < 4; ++nj) {
            const int row = wn * 64 + nj * 16 + l16;
            bf[nj] = *(const short8*)&bs[row * 32 + (quad ^ csw) * 8];
        }
#pragma unroll
        for (int mi = 0; mi < 4; ++mi) {
            const int row = wm * 128 + mi * 16 + l16;
            af[mi] = *(const short8*)&as[row * 32 + (quad ^ csw) * 8];
        }
        if (h + 2 < NHS) stageA(h + 2);
        __builtin_amdgcn_s_barrier();
        asm volatile("s_waitcnt lgkmcnt(0)" ::: "memory");
        __builtin_amdgcn_sched_barrier(0);
        __builtin_amdgcn_s_setprio(1);
#pragma unroll
        for (int mi = 0; mi < 4; ++mi)
#pragma unroll
            for (int nj = 0; nj < 4; ++nj)
                acc[mi][nj] = __builtin_amdgcn_mfma_f32_16x16x32_bf16(af[mi], bf[nj], acc[mi][nj], 0, 0, 0);
        __builtin_amdgcn_s_setprio(0);
        __builtin_amdgcn_s_barrier();

        // ---- phase B: af[4..7], stage B(h+2), 16 MFMA, counted vmcnt ----
#pragma unroll
        for (int mi = 4; mi < 8; ++mi) {
            const int row = wm * 128 + mi * 16 + l16;
            af[mi] = *(const short8*)&as[row * 32 + (quad ^ csw) * 8];
        }
        if (h + 2 < NHS) stageB(h + 2);
        __builtin_amdgcn_s_barrier();
        asm volatile("s_waitcnt lgkmcnt(0)" ::: "memory");
        __builtin_amdgcn_sched_barrier(0);
        __builtin_amdgcn_s_setprio(1);
#pragma unroll
        for (int mi = 4; mi < 8; ++mi)
#pragma unroll
            for (int nj = 0; nj < 4; ++nj)
                acc[mi][nj] = __builtin_amdgcn_mfma_f32_16x16x32_bf16(af[mi], bf[nj], acc[mi][nj], 0, 0, 0);
        __builtin_amdgcn_s_setprio(0);
        // retire half-step h+1's 4 loads (leave h+2's in flight); tail drains
        if (h + 2 < NHS)      asm volatile("s_waitcnt vmcnt(4)" ::: "memory");
        else                  asm volatile("s_waitcnt vmcnt(0)" ::: "memory");
        __builtin_amdgcn_sched_barrier(0);
        __builtin_amdgcn_s_barrier();
    }

    if (region < 2) {
        __hip_bfloat16* C    = (region == 0) ? Qb : Kb;
        const float*    bias = (region == 0) ? bq : bk;
        const float     scl  = (region == 0) ? qscl : 1.0f;
#pragma unroll
        for (int j = 0; j < 4; ++j) {
            const int col = nl + wn * 64 + j * 16 + l16;
            const float bvv = bias[col];
#pragma unroll
            for (int mi = 0; mi < 8; ++mi) {
#pragma unroll
                for (int r = 0; r < 4; ++r) {
                    const int row = m0 + wm * 128 + mi * 16 + quad * 4 + r;
                    C[(size_t)row * 1024 + col] = __float2bfloat16((acc[mi][j][r] + bvv) * scl);
                }
            }
        }
    } else {
        // V transposed per head: addr = (b*1024 + col)*2048 + j.
#pragma unroll
        for (int j = 0; j < 4; ++j) {
            const int col = nl + wn * 64 + j * 16 + l16;
            const float bvv = bv[col];
#pragma unroll
            for (int mi = 0; mi < 8; ++mi) {
                const int row0 = m0 + wm * 128 + mi * 16 + quad * 4;
                union { __hip_bfloat16 h4[4]; uint2 u; } pk;
#pragma unroll
                for (int r = 0; r < 4; ++r)
                    pk.h4[r] = __float2bfloat16(acc[mi][j][r] + bvv);
                *(uint2*)&Vt[((size_t)((row0 >> 11) * 1024 + col)) * 2048 + (row0 & 2047)] = pk.u;
            }
        }
    }
}

// ---------------------------------------------------------------------------
// O-projection GEMM: 64x128 tile, XCD-rect, f32 out; 3-buffer depth-2
// counted-vmcnt pipeline (3 async16/stage -> vmcnt(3|0)).
// ---------------------------------------------------------------------------
__global__ __launch_bounds__(256) void gemm_o(
    const __hip_bfloat16* __restrict__ A,    // [M,1024]
    const __hip_bfloat16* __restrict__ Bt,   // [1024,1024] (Wot)
    const float* __restrict__ bias,
    float* __restrict__ C,                   // [M,1024] f32
    int M)
{
    constexpr int BM = 64, BN = 128, BK = 32, Kd = 1024, NIT = Kd / BK;
    __shared__ __align__(16) __hip_bfloat16 As[3][BM * BK];  // 3 x 4 KB
    __shared__ __align__(16) __hip_bfloat16 Bs[3][BN * BK];  // 3 x 8 KB

    const int t    = threadIdx.x;
    const int w    = t >> 6;
    const int lane = t & 63;
    const int quad = lane >> 4;
    const int l16  = lane & 15;
    const int wm   = w & 1;         // 2 m-halves of 32 rows
    const int wn   = w >> 1;        // 2 n-halves of 64 cols

    // XCD-rect decode: 512 = 8 XCD x (4bx x 16by)
    const int f  = blockIdx.x;
    const int rx = f & 7;
    const int rr = f >> 3;               // 0..63
    const int bx = (rx & 1) * 4 + (rr & 3);
    const int by = (rx >> 1) * 16 + (rr >> 2);
    const int m0 = by * BM;
    const int n0 = bx * BN;

    const int lrow = lane >> 2;
    const int lcol = (lane & 3) * 8;

    floatx4 acc[2][4];
#pragma unroll
    for (int i = 0; i < 2; ++i)
#pragma unroll
        for (int j = 0; j < 4; ++j) acc[i][j] = (floatx4){0.f, 0.f, 0.f, 0.f};

    // 12 segments (4 A + 8 B), 3 per wave
    auto stage = [&](int k0, int buf) {
#pragma unroll
        for (int s = 0; s < 3; ++s) {
            const int seg = w * 3 + s;
            if (seg < 4) {
                async16(A + (size_t)(m0 + seg * 16 + lrow) * Kd + k0 + lcol,
                        &As[buf][seg * 16 * BK]);
            } else {
                const int bs = seg - 4;
                async16(Bt + (size_t)(n0 + bs * 16 + lrow) * Kd + k0 + lcol,
                        &Bs[buf][bs * 16 * BK]);
            }
        }
    };

    stage(0, 0);
    stage(BK, 1);
    int cur = 0;
    for (int i = 0; i < NIT; ++i) {
        if (i < NIT - 1) asm volatile("s_waitcnt vmcnt(3)" ::: "memory");
        else             asm volatile("s_waitcnt vmcnt(0)" ::: "memory");
        __builtin_amdgcn_sched_barrier(0);
        __builtin_amdgcn_s_barrier();
        if (i + 2 < NIT) stage((i + 2) * BK, (cur + 2 >= 3) ? cur - 1 : cur + 2);

        short8 af[2], bf[4];
#pragma unroll
        for (int ii = 0; ii < 2; ++ii)
            af[ii] = *(const short8*)&As[cur][(wm * 32 + ii * 16 + l16) * BK + quad * 8];
#pragma unroll
        for (int j = 0; j < 4; ++j)
            bf[j] = *(const short8*)&Bs[cur][(wn * 64 + j * 16 + l16) * BK + quad * 8];
#pragma unroll
        for (int ii = 0; ii < 2; ++ii)
#pragma unroll
            for (int j = 0; j < 4; ++j)
                acc[ii][j] = __builtin_amdgcn_mfma_f32_16x16x32_bf16(af[ii], bf[j], acc[ii][j], 0, 0, 0);
        cur = (cur + 1 >= 3) ? 0 : cur + 1;
    }

#pragma unroll
    for (int j = 0; j < 4; ++j) {
        const int col = n0 + wn * 64 + j * 16 + l16;
        const float bvf = bias[col];
#pragma unroll
        for (int i = 0; i < 2; ++i) {
#pragma unroll
            for (int r = 0; r < 4; ++r) {
                const int row = m0 + wm * 32 + i * 16 + quad * 4 + r;
                C[(size_t)row * 1024 + col] = acc[i][j][r] + bvf;
            }
        }
    }
}

// ---------------------------------------------------------------------------
// Fallback GEMM (fp32 inputs, fused convert, 64x64 tile). TRANSV writes the
// output per-head-transposed into Vt layout.
// ---------------------------------------------------------------------------
template <bool A_IS_F32, bool OUT_F32, bool TRANSV = false>
__global__ __launch_bounds__(256) void gemm64(
    const void* __restrict__ Av,
    const float* __restrict__ B,
    const float* __restrict__ bias,
    void* __restrict__ Cv,
    int M, int N, int K, float scale)
{
    __shared__ __align__(16) __hip_bfloat16 As[64][40];
    __shared__ __align__(16) __hip_bfloat16 Bs[64][40];

    const int t    = threadIdx.x;
    const int wave = t >> 6;
    const int lane = t & 63;
    const int quad = lane >> 4;
    const int l16  = lane & 15;
    const int m0   = blockIdx.y * 64;
    const int n0   = blockIdx.x * 64;

    floatx4 acc[4];
#pragma unroll
    for (int i = 0; i < 4; ++i) acc[i] = (floatx4){0.f, 0.f, 0.f, 0.f};

    const int arow = t >> 2, acol = (t & 3) * 8;
    const int bkk  = t >> 3, bnn  = (t & 7) * 8;

    for (int k0 = 0; k0 < K; k0 += 32) {
        if constexpr (A_IS_F32) {
            const float* A = (const float*)Av;
            const float* ap = A + (size_t)(m0 + arow) * K + k0 + acol;
            float4 a0 = ((const float4*)ap)[0];
            float4 a1 = ((const float4*)ap)[1];
            union { __hip_bfloat16 h[8]; short8 s; } up;
            up.h[0] = __float2bfloat16(a0.x); up.h[1] = __float2bfloat16(a0.y);
            up.h[2] = __float2bfloat16(a0.z); up.h[3] = __float2bfloat16(a0.w);
            up.h[4] = __float2bfloat16(a1.x); up.h[5] = __float2bfloat16(a1.y);
            up.h[6] = __float2bfloat16(a1.z); up.h[7] = __float2bfloat16(a1.w);
            *(short8*)(&As[arow][acol]) = up.s;
        } else {
            const __hip_bfloat16* A = (const __hip_bfloat16*)Av;
            uint4 av = *(const uint4*)(A + (size_t)(m0 + arow) * K + k0 + acol);
            *(uint4*)(&As[arow][acol]) = av;
        }
        {
            const float* bp = B + (size_t)(k0 + bkk) * N + n0 + bnn;
            float4 b0 = ((const float4*)bp)[0];
            float4 b1 = ((const float4*)bp)[1];
            Bs[bnn + 0][bkk] = __float2bfloat16(b0.x);
            Bs[bnn + 1][bkk] = __float2bfloat16(b0.y);
            Bs[bnn + 2][bkk] = __float2bfloat16(b0.z);
            Bs[bnn + 3][bkk] = __float2bfloat16(b0.w);
            Bs[bnn + 4][bkk] = __float2bfloat16(b1.x);
            Bs[bnn + 5][bkk] = __float2bfloat16(b1.y);
            Bs[bnn + 6][bkk] = __float2bfloat16(b1.z);
            Bs[bnn + 7][bkk] = __float2bfloat16(b1.w);
        }
        __syncthreads();

        short8 afrag = *(const short8*)(&As[wave * 16 + l16][quad * 8]);
#pragma unroll
        for (int nt = 0; nt < 4; ++nt) {
            short8 bfrag = *(const short8*)(&Bs[nt * 16 + l16][quad * 8]);
            acc[nt] = __builtin_amdgcn_mfma_f32_16x16x32_bf16(afrag, bfrag, acc[nt], 0, 0, 0);
        }
        __syncthreads();
    }

#pragma unroll
    for (int nt = 0; nt < 4; ++nt) {
        const int col = n0 + nt * 16 + l16;
        const float bvf = bias[col];
        if constexpr (TRANSV) {
            const int row0 = m0 + wave * 16 + quad * 4;
            union { __hip_bfloat16 h4[4]; uint2 u; } pk;
#pragma unroll
            for (int r = 0; r < 4; ++r)
                pk.h4[r] = __float2bfloat16(acc[nt][r] + bvf);
            *(uint2*)&((__hip_bfloat16*)Cv)[((size_t)((row0 >> 11) * 1024 + col)) * 2048 + (row0 & 2047)] = pk.u;
        } else {
#pragma unroll
            for (int r = 0; r < 4; ++r) {
                const int row = m0 + wave * 16 + quad * 4 + r;
                const float v = (acc[nt][r] + bvf) * scale;
                if constexpr (OUT_F32) ((float*)Cv)[(size_t)row * N + col] = v;
                else ((__hip_bfloat16*)Cv)[(size_t)row * N + col] = __float2bfloat16(v);
            }
        }
    }
}

// ---------------------------------------------------------------------------
// MFMA flash attention v10 (round-7 proven, unchanged): XCD-clustered +
// causal balance pairing (34 iters/CU), 3-buffer depth-2 counted vmcnt,
// race-safe post-barrier staging, setprio around PV.
// ---------------------------------------------------------------------------
#define PP 72                 // P/Q row pitch (144 B = 9*16B, aligned)

__global__ __launch_bounds__(256, 2) void attn_mfma10(
    const __hip_bfloat16* __restrict__ Q,
    const __hip_bfloat16* __restrict__ K,
    const __hip_bfloat16* __restrict__ Vt,   // [b][h][64 d][2048 j]
    __hip_bfloat16* __restrict__ O)
{
    __shared__ __align__(16) __hip_bfloat16 KtS[3][64 * 64];  // 3 x 8 KB, swizzled rows
    __shared__ __align__(16) __hip_bfloat16 VtS[3][64 * 64];  // 3 x 8 KB, swizzled rows
    __shared__ __align__(16) __hip_bfloat16 PsQ[128 * PP];    // 18 KB: Q stage, then per-wave P

    const int t    = threadIdx.x;
    const int w    = t >> 6;
    const int lane = t & 63;
    const int quad = lane >> 4;
    const int l16  = lane & 15;

    // XCD-clustered + balance-paired decode
    const int f   = blockIdx.x;
    const int xcd = f & 7;
    const int u   = f >> 3;        // 0..63
    const int pi  = u >> 4;        // 0..3 (pair index within XCD)
    const int qr  = u & 15;
    const int qx  = (pi & 2) ? (15 - qr) : qr;   // second round flips -> 34 iters/CU
    const int p   = xcd * 4 + pi;  // (b,h) pair 0..31
    const int h   = p & 15;
    const int b   = p >> 4;
    const int q0  = qx * 128;

    const size_t rowbase = (size_t)b * LQ;
    const int    hcol    = h * 64;
    const size_t vbase   = (size_t)(b * NH + h) * 64 * LQ;

    const int r8 = l16 & 7;

    // stage K and V^T 64x64 tiles; LDS linear dest, source chunk-swizzled so
    // that swizzled reads (chunk ^ row&7) return logical data. 4 async16/thr.
    auto stage = [&](int j0n, int buf) {
#pragma unroll
        for (int rnd = 0; rnd < 2; ++rnd) {
            const int c   = rnd * 256 + t;          // 16B chunk index, 0..511
            const int row = c >> 3;                 // 0..63
            const int ch  = (c & 7) ^ (row & 7);    // swizzled source chunk
            async16(K + (rowbase + j0n + row) * DM + hcol + ch * 8,
                    &KtS[buf][c * 8]);
            async16(Vt + vbase + (size_t)row * LQ + j0n + ch * 8,
                    &VtS[buf][c * 8]);
        }
    };

    // ---- Q tile (128 rows x 64) -> LDS (wave-local rows: no barrier) ----
    {
        const int qrow = t >> 1, qseg = (t & 1) * 32;   // 64B per thread
        const uint4* src = (const uint4*)(Q + (rowbase + q0 + qrow) * DM + hcol + qseg);
        uint4* dst = (uint4*)&PsQ[qrow * PP + qseg];
        dst[0] = src[0]; dst[1] = src[1]; dst[2] = src[2]; dst[3] = src[3];
    }
    stage(0, 0);
    stage(64, 1);

    // qf reads own wave's rows (ordered vs own stores by lgkmcnt)
    short8 qf[2][2];
#pragma unroll
    for (int g = 0; g < 2; ++g)
#pragma unroll
        for (int hh = 0; hh < 2; ++hh)
            qf[g][hh] = *(const short8*)&PsQ[(w * 32 + g * 16 + l16) * PP + hh * 32 + quad * 8];

    __hip_bfloat16* Pw = &PsQ[(w * 32) * PP];  // wave-private P[32 q][64 j]

    float l_i[2] = {0.f, 0.f};
    floatx4 o[2][4];
#pragma unroll
    for (int g = 0; g < 2; ++g)
#pragma unroll
        for (int i = 0; i < 4; ++i) o[g][i] = (floatx4){0.f, 0.f, 0.f, 0.f};

    const int wq_lo  = q0 + w * 32;       // first q row of this wave
    const int wq_hi  = wq_lo + 31;
    const int ntiles = 2 * qx + 2;

    int cur = 0;
    for (int jt = 0; jt < ntiles; ++jt) {
        const int j0 = jt * 64;

        // retire own stage(jt) (4 loads), keep stage(jt+1) in flight
        if (jt < ntiles - 1) asm volatile("s_waitcnt vmcnt(4)" ::: "memory");
        else                 asm volatile("s_waitcnt vmcnt(0)" ::: "memory");
        __builtin_amdgcn_sched_barrier(0);
        __builtin_amdgcn_s_barrier();
        // safe: buffer (cur+2)%3 was retired by the barrier above
        if (jt + 2 < ntiles) stage(j0 + 128, (cur + 2 >= 3) ? cur - 1 : cur + 2);

        if (j0 <= wq_hi) {
            const bool bnd = (j0 + 63 > wq_lo);   // boundary: needs causal mask
            // ---- S^T = K * Q^T, fused softmax numerator per (g, jc) ----
#pragma unroll
            for (int jc = 0; jc < 4; ++jc) {
                const __hip_bfloat16* kr = &KtS[cur][(jc * 16 + l16) * 64];
                short8 ak0 = *(const short8*)&kr[((quad    ) ^ r8) * 8];
                short8 ak1 = *(const short8*)&kr[((quad + 4) ^ r8) * 8];
#pragma unroll
                for (int g = 0; g < 2; ++g) {
                    floatx4 z = (floatx4){0.f, 0.f, 0.f, 0.f};
                    z = __builtin_amdgcn_mfma_f32_16x16x32_bf16(ak0, qf[g][0], z, 0, 0, 0);
                    z = __builtin_amdgcn_mfma_f32_16x16x32_bf16(ak1, qf[g][1], z, 0, 0, 0);
                    if (bnd) {
                        const int qg = wq_lo + g * 16 + l16;
#pragma unroll
                        for (int r = 0; r < 4; ++r) {
                            const int j = j0 + jc * 16 + quad * 4 + r;
                            if (j > qg) z[r] = -1e30f;
                        }
                    }
                    union { __hip_bfloat16 h4[4]; uint2 u; } pk;
#pragma unroll
                    for (int r = 0; r < 4; ++r) {
                        const float e = __builtin_amdgcn_exp2f(z[r]);
                        l_i[g] += e;
                        pk.h4[r] = __float2bfloat16(e);
                    }
                    *(uint2*)&Pw[(g * 16 + l16) * PP + jc * 16 + quad * 4] = pk.u;
                }
            }
            // ---- P frags (wave-local write->read) ----
            short8 pa[2][2];
#pragma unroll
            for (int g = 0; g < 2; ++g) {
                pa[g][0] = *(const short8*)&Pw[(g * 16 + l16) * PP + quad * 8];
                pa[g][1] = *(const short8*)&Pw[(g * 16 + l16) * PP + 32 + quad * 8];
            }
            // ---- O += P * V (pure-MFMA cluster: setprio) ----
            __builtin_amdgcn_s_setprio(1);
#pragma unroll
            for (int subf = 0; subf < 4; ++subf) {
                const __hip_bfloat16* vr = &VtS[cur][(subf * 16 + l16) * 64];
                short8 vb0 = *(const short8*)&vr[((quad    ) ^ r8) * 8];
                short8 vb1 = *(const short8*)&vr[((quad + 4) ^ r8) * 8];
#pragma unroll
                for (int g = 0; g < 2; ++g) {
                    o[g][subf] = __builtin_amdgcn_mfma_f32_16x16x32_bf16(pa[g][0], vb0, o[g][subf], 0, 0, 0);
                    o[g][subf] = __builtin_amdgcn_mfma_f32_16x16x32_bf16(pa[g][1], vb1, o[g][subf], 0, 0, 0);
                }
            }
            __builtin_amdgcn_s_setprio(0);
        }
        cur = (cur + 1 >= 3) ? 0 : cur + 1;
    }

#pragma unroll
    for (int g = 0; g < 2; ++g) {
        l_i[g] += __shfl_xor(l_i[g], 16);
        l_i[g] += __shfl_xor(l_i[g], 32);
#pragma unroll
        for (int r = 0; r < 4; ++r) {
            const float linv = 1.0f / __shfl(l_i[g], quad * 4 + r);
            const size_t row = rowbase + q0 + w * 32 + g * 16 + quad * 4 + r;
#pragma unroll
            for (int subf = 0; subf < 4; ++subf)
                O[row * DM + hcol + subf * 16 + l16] = __float2bfloat16(o[g][subf][r] * linv);
        }
    }
}

// ---------------------------------------------------------------------------
extern "C" void kernel_launch(void* const* d_in, const int* in_sizes, int n_in,
                              void* d_out, int out_size, void* d_ws, size_t ws_size,
                              hipStream_t stream)
{
    (void)in_sizes; (void)n_in; (void)out_size;

    const float* x  = (const float*)d_in[0];
    const float* y  = (const float*)d_in[1];
    // d_in[2] = mask: causal tril, handled analytically
    const float* Wq = (const float*)d_in[3];
    const float* bq = (const float*)d_in[4];
    const float* Wk = (const float*)d_in[5];
    const float* bk = (const float*)d_in[6];
    const float* Wv = (const float*)d_in[7];
    const float* bv = (const float*)d_in[8];
    const float* Wo = (const float*)d_in[9];
    const float* bo = (const float*)d_in[10];

    const size_t NTOK = (size_t)2 * LQ * DM;   // 4,194,304
    const size_t MM   = (size_t)DM * DM;       // 1,048,576
    const int    M    = 2 * LQ;                // 4096
    const float  QSCL = 0.125f * LOG2E;        // 1/sqrt(dk) * log2(e): exp2-domain softmax

    __hip_bfloat16* Qb  = (__hip_bfloat16*)d_ws;
    __hip_bfloat16* Kb  = Qb + NTOK;
    __hip_bfloat16* Vtb = Kb + NTOK;           // transposed V: [b][h][64][2048]
    __hip_bfloat16* Ab  = Vtb + NTOK;

    const size_t need = (4 * NTOK + 2 * NTOK + 4 * MM) * sizeof(__hip_bfloat16);
    const dim3 agrid(512, 1, 1);  // flat, XCD-clustered decode in-kernel

    if (ws_size >= need) {
        __hip_bfloat16* xb  = Ab + NTOK;
        __hip_bfloat16* yb  = xb + NTOK;
        __hip_bfloat16* Wqt = yb + NTOK;
        __hip_bfloat16* Wkt = Wqt + MM;   // [Wqt; Wkt; Wvt] contiguous = stacked QKV B
        __hip_bfloat16* Wvt = Wkt + MM;
        __hip_bfloat16* Wot = Wvt + MM;
        (void)Wkt; (void)Wvt;

        prep_all<<<5120, 256, 0, stream>>>(x, y, Wq, Wk, Wv, Wo,
                                           xb, yb, Wqt, Wkt, Wvt, Wot);

        gemm_qkv<<<192, 512, 0, stream>>>(xb, yb, Wqt, bq, bk, bv, Qb, Kb, Vtb, QSCL);
        attn_mfma10<<<agrid, 256, 0, stream>>>(Qb, Kb, Vtb, Ab);
        gemm_o<<<512, 256, 0, stream>>>(Ab, Wot, bo, (float*)d_out, M);
    } else {
        const dim3 gblk(DM / 64, M / 64);
        gemm64<true,  false><<<gblk, 256, 0, stream>>>(x, Wq, bq, Qb, M, DM, DM, QSCL);
        gemm64<true,  false><<<gblk, 256, 0, stream>>>(y, Wk, bk, Kb, M, DM, DM, 1.0f);
        gemm64<true,  false, true><<<gblk, 256, 0, stream>>>(y, Wv, bv, Vtb, M, DM, DM, 1.0f);
        attn_mfma10<<<agrid, 256, 0, stream>>>(Qb, Kb, Vtb, Ab);
        gemm64<false, true ><<<gblk, 256, 0, stream>>>(Ab, Wo, bo, (float*)d_out, M, DM, DM, 1.0f);
    }
}

// Round 11
// 213.357 us; speedup vs baseline: 1.0652x; 1.0162x over previous
//
#include <hip/hip_runtime.h>
#include <hip/hip_bf16.h>

typedef __attribute__((ext_vector_type(8))) short short8;   // 8 bf16 = 4 VGPRs (MFMA A/B frag)
typedef __attribute__((ext_vector_type(4))) float floatx4;  // MFMA C/D frag

#define LQ 2048
#define DM 1024
#define NH 16
#define LOG2E 1.44269504088896f

typedef __attribute__((address_space(1))) void gas_t;
typedef __attribute__((address_space(3))) void las_t;

// async global->LDS, 16B per lane; LDS dest = wave-uniform base + lane*16
__device__ __forceinline__ void async16(const __hip_bfloat16* g, __hip_bfloat16* l) {
    __builtin_amdgcn_global_load_lds((gas_t*)g, (las_t*)l, 16, 0, 0);
}

// ---------------------------------------------------------------------------
// Fused prep: blocks [0,2048) convert x; [2048,4096) convert y;
// [4096,5120) transpose-convert the 4 weight matrices (64x64 tiles).
// ---------------------------------------------------------------------------
__global__ __launch_bounds__(256) void prep_all(
    const float* __restrict__ x,  const float* __restrict__ y,
    const float* __restrict__ Wq, const float* __restrict__ Wk,
    const float* __restrict__ Wv, const float* __restrict__ Wo,
    __hip_bfloat16* __restrict__ xb,  __hip_bfloat16* __restrict__ yb,
    __hip_bfloat16* __restrict__ Wqt, __hip_bfloat16* __restrict__ Wkt,
    __hip_bfloat16* __restrict__ Wvt, __hip_bfloat16* __restrict__ Wot)
{
    __shared__ float tile[64][65];
    const int t  = threadIdx.x;
    const int bx = blockIdx.x;

    if (bx < 4096) {
        const float* in = (bx < 2048) ? x : y;
        __hip_bfloat16* out = (bx < 2048) ? xb : yb;
        const int i = ((bx & 2047) * 256 + t) * 8;
        float4 a0 = ((const float4*)(in + i))[0];
        float4 a1 = ((const float4*)(in + i))[1];
        union { __hip_bfloat16 h[8]; uint4 u; } pk;
        pk.h[0] = __float2bfloat16(a0.x); pk.h[1] = __float2bfloat16(a0.y);
        pk.h[2] = __float2bfloat16(a0.z); pk.h[3] = __float2bfloat16(a0.w);
        pk.h[4] = __float2bfloat16(a1.x); pk.h[5] = __float2bfloat16(a1.y);
        pk.h[6] = __float2bfloat16(a1.z); pk.h[7] = __float2bfloat16(a1.w);
        *(uint4*)(out + i) = pk.u;
        return;
    }

    const int r    = bx - 4096;       // 0..1023
    const int wsel = r >> 8;          // 0..3
    const int tid  = r & 255;
    const int n0   = (tid & 15) * 64, k0 = (tid >> 4) * 64;
    const float* W = (wsel == 0) ? Wq : (wsel == 1) ? Wk : (wsel == 2) ? Wv : Wo;
    __hip_bfloat16* Wt = (wsel == 0) ? Wqt : (wsel == 1) ? Wkt : (wsel == 2) ? Wvt : Wot;

    const int rr0 = t >> 4, c4 = (t & 15) * 4;
#pragma unroll
    for (int rr = 0; rr < 64; rr += 16) {
        float4 v = *(const float4*)&W[(size_t)(k0 + rr0 + rr) * DM + n0 + c4];
        tile[rr0 + rr][c4 + 0] = v.x; tile[rr0 + rr][c4 + 1] = v.y;
        tile[rr0 + rr][c4 + 2] = v.z; tile[rr0 + rr][c4 + 3] = v.w;
    }
    __syncthreads();
    const int nr = t >> 2, kc = (t & 3) * 16;
    union { __hip_bfloat16 h[16]; uint4 u[2]; } pk;
#pragma unroll
    for (int i = 0; i < 16; ++i) pk.h[i] = __float2bfloat16(tile[kc + i][nr]);
    uint4* dst = (uint4*)&Wt[(size_t)(n0 + nr) * DM + k0 + kc];
    dst[0] = pk.u[0];
    dst[1] = pk.u[1];
}

// ---------------------------------------------------------------------------
// Fused QKV GEMM v4 (round-10 proven, unchanged): 256x256, 8 waves, m201-style
// phase schedule, 4 rotating K-half slots, counted vmcnt, T2 swizzle.
// ---------------------------------------------------------------------------
__global__ __launch_bounds__(512) void gemm_qkv(
    const __hip_bfloat16* __restrict__ xb,
    const __hip_bfloat16* __restrict__ yb,
    const __hip_bfloat16* __restrict__ Bt,   // Wqt (Wkt, Wvt contiguous after)
    const float* __restrict__ bq, const float* __restrict__ bk,
    const float* __restrict__ bv,
    __hip_bfloat16* __restrict__ Qb, __hip_bfloat16* __restrict__ Kb,
    __hip_bfloat16* __restrict__ Vt,
    float qscl)
{
    constexpr int BM = 256, BN = 256, Kd = 1024;
    constexpr int NHS = Kd / 32;                 // 32 K-half steps
    __shared__ __align__(16) __hip_bfloat16 As[4][256 * 32];  // 4 x 16 KB
    __shared__ __align__(16) __hip_bfloat16 Bs[4][256 * 32];  // 4 x 16 KB

    const int t    = threadIdx.x;
    const int w    = t >> 6;        // 0..7
    const int lane = t & 63;
    const int quad = lane >> 4;
    const int l16  = lane & 15;
    const int wm   = w & 1;         // 2 m-halves of 128 rows
    const int wn   = w >> 1;        // 4 n-quarters of 64 cols

    // XCD-rect decode: 192 = 8 XCD x (6bx x 4by); n-tiles 12, m-tiles 16
    const int f  = blockIdx.x;
    const int rx = f & 7;
    const int rr = f >> 3;               // 0..23
    const int bx = (rx & 1) * 6 + rr % 6;
    const int by = (rx >> 1) * 4 + rr / 6;
    const int m0 = by * BM;
    const int n0 = bx * BN;

    const int region = n0 >> 10;             // 0=Q 1=K 2=V (block-uniform)
    const int nl     = n0 & 1023;

    const __hip_bfloat16* A = (region == 0) ? xb : yb;

    floatx4 acc[8][4];
#pragma unroll
    for (int i = 0; i < 8; ++i)
#pragma unroll
        for (int j = 0; j < 4; ++j) acc[i][j] = (floatx4){0.f, 0.f, 0.f, 0.f};

    auto stageA = [&](int h) {
        const int k0 = h * 32, slot = h & 3;
#pragma unroll
        for (int l = 0; l < 2; ++l) {
            const int c   = l * 512 + t;
            const int row = c >> 2;
            const int ch  = (c & 3) ^ ((row >> 1) & 3);
            async16(A + (size_t)(m0 + row) * Kd + k0 + ch * 8, &As[slot][c * 8]);
        }
    };
    auto stageB = [&](int h) {
        const int k0 = h * 32, slot = h & 3;
#pragma unroll
        for (int l = 0; l < 2; ++l) {
            const int c   = l * 512 + t;
            const int row = c >> 2;
            const int ch  = (c & 3) ^ ((row >> 1) & 3);
            async16(Bt + (size_t)(n0 + row) * Kd + k0 + ch * 8, &Bs[slot][c * 8]);
        }
    };

    stageA(0); stageB(0); stageA(1); stageB(1);
    asm volatile("s_waitcnt vmcnt(4)" ::: "memory");
    __builtin_amdgcn_sched_barrier(0);
    __builtin_amdgcn_s_barrier();

    const int csw = (l16 >> 1) & 3;   // read-side chunk swizzle (== (row>>1)&3)

    for (int h = 0; h < NHS; ++h) {
        const int slot = h & 3;
        const __hip_bfloat16* as = &As[slot][0];
        const __hip_bfloat16* bs = &Bs[slot][0];
        short8 af[8], bf[4];

        // ---- phase A ----
#pragma unroll
        for (int nj = 0; nj < 4; ++nj) {
            const int row = wn * 64 + nj * 16 + l16;
            bf[nj] = *(const short8*)&bs[row * 32 + (quad ^ csw) * 8];
        }
#pragma unroll
        for (int mi = 0; mi < 4; ++mi) {
            const int row = wm * 128 + mi * 16 + l16;
            af[mi] = *(const short8*)&as[row * 32 + (quad ^ csw) * 8];
        }
        if (h + 2 < NHS) stageA(h + 2);
        __builtin_amdgcn_s_barrier();
        asm volatile("s_waitcnt lgkmcnt(0)" ::: "memory");
        __builtin_amdgcn_sched_barrier(0);
        __builtin_amdgcn_s_setprio(1);
#pragma unroll
        for (int mi = 0; mi < 4; ++mi)
#pragma unroll
            for (int nj = 0; nj < 4; ++nj)
                acc[mi][nj] = __builtin_amdgcn_mfma_f32_16x16x32_bf16(af[mi], bf[nj], acc[mi][nj], 0, 0, 0);
        __builtin_amdgcn_s_setprio(0);
        __builtin_amdgcn_s_barrier();

        // ---- phase B ----
#pragma unroll
        for (int mi = 4; mi < 8; ++mi) {
            const int row = wm * 128 + mi * 16 + l16;
            af[mi] = *(const short8*)&as[row * 32 + (quad ^ csw) * 8];
        }
        if (h + 2 < NHS) stageB(h + 2);
        __builtin_amdgcn_s_barrier();
        asm volatile("s_waitcnt lgkmcnt(0)" ::: "memory");
        __builtin_amdgcn_sched_barrier(0);
        __builtin_amdgcn_s_setprio(1);
#pragma unroll
        for (int mi = 4; mi < 8; ++mi)
#pragma unroll
            for (int nj = 0; nj < 4; ++nj)
                acc[mi][nj] = __builtin_amdgcn_mfma_f32_16x16x32_bf16(af[mi], bf[nj], acc[mi][nj], 0, 0, 0);
        __builtin_amdgcn_s_setprio(0);
        if (h + 2 < NHS)      asm volatile("s_waitcnt vmcnt(4)" ::: "memory");
        else                  asm volatile("s_waitcnt vmcnt(0)" ::: "memory");
        __builtin_amdgcn_sched_barrier(0);
        __builtin_amdgcn_s_barrier();
    }

    if (region < 2) {
        __hip_bfloat16* C    = (region == 0) ? Qb : Kb;
        const float*    bias = (region == 0) ? bq : bk;
        const float     scl  = (region == 0) ? qscl : 1.0f;
#pragma unroll
        for (int j = 0; j < 4; ++j) {
            const int col = nl + wn * 64 + j * 16 + l16;
            const float bvv = bias[col];
#pragma unroll
            for (int mi = 0; mi < 8; ++mi) {
#pragma unroll
                for (int r = 0; r < 4; ++r) {
                    const int row = m0 + wm * 128 + mi * 16 + quad * 4 + r;
                    C[(size_t)row * 1024 + col] = __float2bfloat16((acc[mi][j][r] + bvv) * scl);
                }
            }
        }
    } else {
#pragma unroll
        for (int j = 0; j < 4; ++j) {
            const int col = nl + wn * 64 + j * 16 + l16;
            const float bvv = bv[col];
#pragma unroll
            for (int mi = 0; mi < 8; ++mi) {
                const int row0 = m0 + wm * 128 + mi * 16 + quad * 4;
                union { __hip_bfloat16 h4[4]; uint2 u; } pk;
#pragma unroll
                for (int r = 0; r < 4; ++r)
                    pk.h4[r] = __float2bfloat16(acc[mi][j][r] + bvv);
                *(uint2*)&Vt[((size_t)((row0 >> 11) * 1024 + col)) * 2048 + (row0 & 2047)] = pk.u;
            }
        }
    }
}

// ---------------------------------------------------------------------------
// O-projection GEMM: 64x128 tile, XCD-rect, f32 out; 3-buffer depth-2
// counted-vmcnt pipeline (3 async16/stage -> vmcnt(3|0)).
// ---------------------------------------------------------------------------
__global__ __launch_bounds__(256) void gemm_o(
    const __hip_bfloat16* __restrict__ A,    // [M,1024]
    const __hip_bfloat16* __restrict__ Bt,   // [1024,1024] (Wot)
    const float* __restrict__ bias,
    float* __restrict__ C,                   // [M,1024] f32
    int M)
{
    constexpr int BM = 64, BN = 128, BK = 32, Kd = 1024, NIT = Kd / BK;
    __shared__ __align__(16) __hip_bfloat16 As[3][BM * BK];  // 3 x 4 KB
    __shared__ __align__(16) __hip_bfloat16 Bs[3][BN * BK];  // 3 x 8 KB

    const int t    = threadIdx.x;
    const int w    = t >> 6;
    const int lane = t & 63;
    const int quad = lane >> 4;
    const int l16  = lane & 15;
    const int wm   = w & 1;         // 2 m-halves of 32 rows
    const int wn   = w >> 1;        // 2 n-halves of 64 cols

    // XCD-rect decode: 512 = 8 XCD x (4bx x 16by)
    const int f  = blockIdx.x;
    const int rx = f & 7;
    const int rr = f >> 3;               // 0..63
    const int bx = (rx & 1) * 4 + (rr & 3);
    const int by = (rx >> 1) * 16 + (rr >> 2);
    const int m0 = by * BM;
    const int n0 = bx * BN;

    const int lrow = lane >> 2;
    const int lcol = (lane & 3) * 8;

    floatx4 acc[2][4];
#pragma unroll
    for (int i = 0; i < 2; ++i)
#pragma unroll
        for (int j = 0; j < 4; ++j) acc[i][j] = (floatx4){0.f, 0.f, 0.f, 0.f};

    // 12 segments (4 A + 8 B), 3 per wave
    auto stage = [&](int k0, int buf) {
#pragma unroll
        for (int s = 0; s < 3; ++s) {
            const int seg = w * 3 + s;
            if (seg < 4) {
                async16(A + (size_t)(m0 + seg * 16 + lrow) * Kd + k0 + lcol,
                        &As[buf][seg * 16 * BK]);
            } else {
                const int bs = seg - 4;
                async16(Bt + (size_t)(n0 + bs * 16 + lrow) * Kd + k0 + lcol,
                        &Bs[buf][bs * 16 * BK]);
            }
        }
    };

    stage(0, 0);
    stage(BK, 1);
    int cur = 0;
    for (int i = 0; i < NIT; ++i) {
        if (i < NIT - 1) asm volatile("s_waitcnt vmcnt(3)" ::: "memory");
        else             asm volatile("s_waitcnt vmcnt(0)" ::: "memory");
        __builtin_amdgcn_sched_barrier(0);
        __builtin_amdgcn_s_barrier();
        if (i + 2 < NIT) stage((i + 2) * BK, (cur + 2 >= 3) ? cur - 1 : cur + 2);

        short8 af[2], bf[4];
#pragma unroll
        for (int ii = 0; ii < 2; ++ii)
            af[ii] = *(const short8*)&As[cur][(wm * 32 + ii * 16 + l16) * BK + quad * 8];
#pragma unroll
        for (int j = 0; j < 4; ++j)
            bf[j] = *(const short8*)&Bs[cur][(wn * 64 + j * 16 + l16) * BK + quad * 8];
#pragma unroll
        for (int ii = 0; ii < 2; ++ii)
#pragma unroll
            for (int j = 0; j < 4; ++j)
                acc[ii][j] = __builtin_amdgcn_mfma_f32_16x16x32_bf16(af[ii], bf[j], acc[ii][j], 0, 0, 0);
        cur = (cur + 1 >= 3) ? 0 : cur + 1;
    }

#pragma unroll
    for (int j = 0; j < 4; ++j) {
        const int col = n0 + wn * 64 + j * 16 + l16;
        const float bvf = bias[col];
#pragma unroll
        for (int i = 0; i < 2; ++i) {
#pragma unroll
            for (int r = 0; r < 4; ++r) {
                const int row = m0 + wm * 32 + i * 16 + quad * 4 + r;
                C[(size_t)row * 1024 + col] = acc[i][j][r] + bvf;
            }
        }
    }
}

// ---------------------------------------------------------------------------
// Fallback GEMM (fp32 inputs, fused convert, 64x64 tile). TRANSV writes the
// output per-head-transposed into Vt layout.
// ---------------------------------------------------------------------------
template <bool A_IS_F32, bool OUT_F32, bool TRANSV = false>
__global__ __launch_bounds__(256) void gemm64(
    const void* __restrict__ Av,
    const float* __restrict__ B,
    const float* __restrict__ bias,
    void* __restrict__ Cv,
    int M, int N, int K, float scale)
{
    __shared__ __align__(16) __hip_bfloat16 As[64][40];
    __shared__ __align__(16) __hip_bfloat16 Bs[64][40];

    const int t    = threadIdx.x;
    const int wave = t >> 6;
    const int lane = t & 63;
    const int quad = lane >> 4;
    const int l16  = lane & 15;
    const int m0   = blockIdx.y * 64;
    const int n0   = blockIdx.x * 64;

    floatx4 acc[4];
#pragma unroll
    for (int i = 0; i < 4; ++i) acc[i] = (floatx4){0.f, 0.f, 0.f, 0.f};

    const int arow = t >> 2, acol = (t & 3) * 8;
    const int bkk  = t >> 3, bnn  = (t & 7) * 8;

    for (int k0 = 0; k0 < K; k0 += 32) {
        if constexpr (A_IS_F32) {
            const float* A = (const float*)Av;
            const float* ap = A + (size_t)(m0 + arow) * K + k0 + acol;
            float4 a0 = ((const float4*)ap)[0];
            float4 a1 = ((const float4*)ap)[1];
            union { __hip_bfloat16 h[8]; short8 s; } up;
            up.h[0] = __float2bfloat16(a0.x); up.h[1] = __float2bfloat16(a0.y);
            up.h[2] = __float2bfloat16(a0.z); up.h[3] = __float2bfloat16(a0.w);
            up.h[4] = __float2bfloat16(a1.x); up.h[5] = __float2bfloat16(a1.y);
            up.h[6] = __float2bfloat16(a1.z); up.h[7] = __float2bfloat16(a1.w);
            *(short8*)(&As[arow][acol]) = up.s;
        } else {
            const __hip_bfloat16* A = (const __hip_bfloat16*)Av;
            uint4 av = *(const uint4*)(A + (size_t)(m0 + arow) * K + k0 + acol);
            *(uint4*)(&As[arow][acol]) = av;
        }
        {
            const float* bp = B + (size_t)(k0 + bkk) * N + n0 + bnn;
            float4 b0 = ((const float4*)bp)[0];
            float4 b1 = ((const float4*)bp)[1];
            Bs[bnn + 0][bkk] = __float2bfloat16(b0.x);
            Bs[bnn + 1][bkk] = __float2bfloat16(b0.y);
            Bs[bnn + 2][bkk] = __float2bfloat16(b0.z);
            Bs[bnn + 3][bkk] = __float2bfloat16(b0.w);
            Bs[bnn + 4][bkk] = __float2bfloat16(b1.x);
            Bs[bnn + 5][bkk] = __float2bfloat16(b1.y);
            Bs[bnn + 6][bkk] = __float2bfloat16(b1.z);
            Bs[bnn + 7][bkk] = __float2bfloat16(b1.w);
        }
        __syncthreads();

        short8 afrag = *(const short8*)(&As[wave * 16 + l16][quad * 8]);
#pragma unroll
        for (int nt = 0; nt < 4; ++nt) {
            short8 bfrag = *(const short8*)(&Bs[nt * 16 + l16][quad * 8]);
            acc[nt] = __builtin_amdgcn_mfma_f32_16x16x32_bf16(afrag, bfrag, acc[nt], 0, 0, 0);
        }
        __syncthreads();
    }

#pragma unroll
    for (int nt = 0; nt < 4; ++nt) {
        const int col = n0 + nt * 16 + l16;
        const float bvf = bias[col];
        if constexpr (TRANSV) {
            const int row0 = m0 + wave * 16 + quad * 4;
            union { __hip_bfloat16 h4[4]; uint2 u; } pk;
#pragma unroll
            for (int r = 0; r < 4; ++r)
                pk.h4[r] = __float2bfloat16(acc[nt][r] + bvf);
            *(uint2*)&((__hip_bfloat16*)Cv)[((size_t)((row0 >> 11) * 1024 + col)) * 2048 + (row0 & 2047)] = pk.u;
        } else {
#pragma unroll
            for (int r = 0; r < 4; ++r) {
                const int row = m0 + wave * 16 + quad * 4 + r;
                const float v = (acc[nt][r] + bvf) * scale;
                if constexpr (OUT_F32) ((float*)Cv)[(size_t)row * N + col] = v;
                else ((__hip_bfloat16*)Cv)[(size_t)row * N + col] = __float2bfloat16(v);
            }
        }
    }
}

// ---------------------------------------------------------------------------
// MFMA flash attention v11 = v10 + T15 2-tile pipeline: PV of tile jt-1 runs
// at iter jt (pure reg/LDS MFMA, overlapping K(jt) ds_reads); the P LDS
// round-trip and the V-read+PV chain move off the serial critical path.
// V gets 4 LDS slots (write jt+2, read jt-1: distance 3 mod 4, never
// collides); K keeps 3. vmcnt arithmetic unchanged (4 loads/stage, depth 2).
// Epilogue flushes the final PV. XCD-clustered + causal balance pairing.
// ---------------------------------------------------------------------------
#define PP 72                 // P/Q row pitch (144 B = 9*16B, aligned)

__global__ __launch_bounds__(256, 2) void attn_mfma11(
    const __hip_bfloat16* __restrict__ Q,
    const __hip_bfloat16* __restrict__ K,
    const __hip_bfloat16* __restrict__ Vt,   // [b][h][64 d][2048 j]
    __hip_bfloat16* __restrict__ O)
{
    __shared__ __align__(16) __hip_bfloat16 KtS[3][64 * 64];  // 24 KB, swizzled rows
    __shared__ __align__(16) __hip_bfloat16 VtS[4][64 * 64];  // 32 KB, swizzled rows
    __shared__ __align__(16) __hip_bfloat16 PsQ[128 * PP];    // 18 KB: Q stage, then per-wave P

    const int t    = threadIdx.x;
    const int w    = t >> 6;
    const int lane = t & 63;
    const int quad = lane >> 4;
    const int l16  = lane & 15;

    // XCD-clustered + balance-paired decode
    const int f   = blockIdx.x;
    const int xcd = f & 7;
    const int u   = f >> 3;        // 0..63
    const int pi  = u >> 4;        // 0..3 (pair index within XCD)
    const int qr  = u & 15;
    const int qx  = (pi & 2) ? (15 - qr) : qr;   // second round flips -> 34 iters/CU
    const int p   = xcd * 4 + pi;  // (b,h) pair 0..31
    const int h   = p & 15;
    const int b   = p >> 4;
    const int q0  = qx * 128;

    const size_t rowbase = (size_t)b * LQ;
    const int    hcol    = h * 64;
    const size_t vbase   = (size_t)(b * NH + h) * 64 * LQ;

    const int r8 = l16 & 7;

    // stage K (slot jt%3) and V^T (slot jt&3) 64x64 tiles; pre-swizzled
    // global source, linear LDS dest. 4 async16/thread per stage.
    auto stage = [&](int j0n, int jtile) {
        const int ks = jtile % 3;
        const int vs = jtile & 3;
#pragma unroll
        for (int rnd = 0; rnd < 2; ++rnd) {
            const int c   = rnd * 256 + t;          // 16B chunk index, 0..511
            const int row = c >> 3;                 // 0..63
            const int ch  = (c & 7) ^ (row & 7);    // swizzled source chunk
            async16(K + (rowbase + j0n + row) * DM + hcol + ch * 8,
                    &KtS[ks][c * 8]);
            async16(Vt + vbase + (size_t)row * LQ + j0n + ch * 8,
                    &VtS[vs][c * 8]);
        }
    };

    // ---- Q tile (128 rows x 64) -> LDS (wave-local rows: no barrier) ----
    {
        const int qrow = t >> 1, qseg = (t & 1) * 32;   // 64B per thread
        const uint4* src = (const uint4*)(Q + (rowbase + q0 + qrow) * DM + hcol + qseg);
        uint4* dst = (uint4*)&PsQ[qrow * PP + qseg];
        dst[0] = src[0]; dst[1] = src[1]; dst[2] = src[2]; dst[3] = src[3];
    }
    stage(0, 0);
    stage(64, 1);

    // qf reads own wave's rows (ordered vs own stores by lgkmcnt)
    short8 qf[2][2];
#pragma unroll
    for (int g = 0; g < 2; ++g)
#pragma unroll
        for (int hh = 0; hh < 2; ++hh)
            qf[g][hh] = *(const short8*)&PsQ[(w * 32 + g * 16 + l16) * PP + hh * 32 + quad * 8];

    __hip_bfloat16* Pw = &PsQ[(w * 32) * PP];  // wave-private P[32 q][64 j]

    float l_i[2] = {0.f, 0.f};
    floatx4 o[2][4];
#pragma unroll
    for (int g = 0; g < 2; ++g)
#pragma unroll
        for (int i = 0; i < 4; ++i) o[g][i] = (floatx4){0.f, 0.f, 0.f, 0.f};

    const int wq_lo  = q0 + w * 32;       // first q row of this wave
    const int wq_hi  = wq_lo + 31;
    const int ntiles = 2 * qx + 2;

    short8 pa[2][2];          // P fragments of the PREVIOUS tile (persist)
    int    pslot = -1;        // V slot of the previous tile; -1 = none

    for (int jt = 0; jt < ntiles; ++jt) {
        const int j0 = jt * 64;

        // retire own stage(jt) (4 loads), keep stage(jt+1) in flight
        if (jt < ntiles - 1) asm volatile("s_waitcnt vmcnt(4)" ::: "memory");
        else                 asm volatile("s_waitcnt vmcnt(0)" ::: "memory");
        __builtin_amdgcn_sched_barrier(0);
        __builtin_amdgcn_s_barrier();
        // safe: K slot (jt+2)%3 and V slot (jt+2)&3 retired by the barrier
        if (jt + 2 < ntiles) stage(j0 + 128, jt + 2);

        const bool active = (j0 <= wq_hi);

        // ---- issue K(jt) fragment reads early (overlap with PV below) ----
        short8 ak[4][2];
        if (active) {
#pragma unroll
            for (int jc = 0; jc < 4; ++jc) {
                const __hip_bfloat16* kr = &KtS[jt % 3][(jc * 16 + l16) * 64];
                ak[jc][0] = *(const short8*)&kr[((quad    ) ^ r8) * 8];
                ak[jc][1] = *(const short8*)&kr[((quad + 4) ^ r8) * 8];
            }
        }

        // ---- PV of PREVIOUS tile (pure MFMA; hides K ds_read latency) ----
        if (pslot >= 0) {
            __builtin_amdgcn_s_setprio(1);
#pragma unroll
            for (int subf = 0; subf < 4; ++subf) {
                const __hip_bfloat16* vr = &VtS[pslot][(subf * 16 + l16) * 64];
                short8 vb0 = *(const short8*)&vr[((quad    ) ^ r8) * 8];
                short8 vb1 = *(const short8*)&vr[((quad + 4) ^ r8) * 8];
#pragma unroll
                for (int g = 0; g < 2; ++g) {
                    o[g][subf] = __builtin_amdgcn_mfma_f32_16x16x32_bf16(pa[g][0], vb0, o[g][subf], 0, 0, 0);
                    o[g][subf] = __builtin_amdgcn_mfma_f32_16x16x32_bf16(pa[g][1], vb1, o[g][subf], 0, 0, 0);
                }
            }
            __builtin_amdgcn_s_setprio(0);
            pslot = -1;
        }

        if (active) {
            const bool bnd = (j0 + 63 > wq_lo);   // boundary: needs causal mask
            // ---- S^T = K * Q^T, fused softmax numerator per (g, jc) ----
            __builtin_amdgcn_s_setprio(1);
#pragma unroll
            for (int jc = 0; jc < 4; ++jc) {
#pragma unroll
                for (int g = 0; g < 2; ++g) {
                    floatx4 z = (floatx4){0.f, 0.f, 0.f, 0.f};
                    z = __builtin_amdgcn_mfma_f32_16x16x32_bf16(ak[jc][0], qf[g][0], z, 0, 0, 0);
                    z = __builtin_amdgcn_mfma_f32_16x16x32_bf16(ak[jc][1], qf[g][1], z, 0, 0, 0);
                    if (bnd) {
                        const int qg = wq_lo + g * 16 + l16;
#pragma unroll
                        for (int r = 0; r < 4; ++r) {
                            const int j = j0 + jc * 16 + quad * 4 + r;
                            if (j > qg) z[r] = -1e30f;
                        }
                    }
                    union { __hip_bfloat16 h4[4]; uint2 u; } pk;
#pragma unroll
                    for (int r = 0; r < 4; ++r) {
                        const float e = __builtin_amdgcn_exp2f(z[r]);
                        l_i[g] += e;
                        pk.h4[r] = __float2bfloat16(e);
                    }
                    *(uint2*)&Pw[(g * 16 + l16) * PP + jc * 16 + quad * 4] = pk.u;
                }
            }
            __builtin_amdgcn_s_setprio(0);
            // ---- P frags for NEXT iter's PV (wave-local write->read) ----
#pragma unroll
            for (int g = 0; g < 2; ++g) {
                pa[g][0] = *(const short8*)&Pw[(g * 16 + l16) * PP + quad * 8];
                pa[g][1] = *(const short8*)&Pw[(g * 16 + l16) * PP + 32 + quad * 8];
            }
            pslot = jt & 3;
        }
    }

    // ---- flush final PV (V slot of the last active tile is not reused) ----
    if (pslot >= 0) {
#pragma unroll
        for (int subf = 0; subf < 4; ++subf) {
            const __hip_bfloat16* vr = &VtS[pslot][(subf * 16 + l16) * 64];
            short8 vb0 = *(const short8*)&vr[((quad    ) ^ r8) * 8];
            short8 vb1 = *(const short8*)&vr[((quad + 4) ^ r8) * 8];
#pragma unroll
            for (int g = 0; g < 2; ++g) {
                o[g][subf] = __builtin_amdgcn_mfma_f32_16x16x32_bf16(pa[g][0], vb0, o[g][subf], 0, 0, 0);
                o[g][subf] = __builtin_amdgcn_mfma_f32_16x16x32_bf16(pa[g][1], vb1, o[g][subf], 0, 0, 0);
            }
        }
    }

#pragma unroll
    for (int g = 0; g < 2; ++g) {
        l_i[g] += __shfl_xor(l_i[g], 16);
        l_i[g] += __shfl_xor(l_i[g], 32);
#pragma unroll
        for (int r = 0; r < 4; ++r) {
            const float linv = 1.0f / __shfl(l_i[g], quad * 4 + r);
            const size_t row = rowbase + q0 + w * 32 + g * 16 + quad * 4 + r;
#pragma unroll
            for (int subf = 0; subf < 4; ++subf)
                O[row * DM + hcol + subf * 16 + l16] = __float2bfloat16(o[g][subf][r] * linv);
        }
    }
}

// ---------------------------------------------------------------------------
extern "C" void kernel_launch(void* const* d_in, const int* in_sizes, int n_in,
                              void* d_out, int out_size, void* d_ws, size_t ws_size,
                              hipStream_t stream)
{
    (void)in_sizes; (void)n_in; (void)out_size;

    const float* x  = (const float*)d_in[0];
    const float* y  = (const float*)d_in[1];
    // d_in[2] = mask: causal tril, handled analytically
    const float* Wq = (const float*)d_in[3];
    const float* bq = (const float*)d_in[4];
    const float* Wk = (const float*)d_in[5];
    const float* bk = (const float*)d_in[6];
    const float* Wv = (const float*)d_in[7];
    const float* bv = (const float*)d_in[8];
    const float* Wo = (const float*)d_in[9];
    const float* bo = (const float*)d_in[10];

    const size_t NTOK = (size_t)2 * LQ * DM;   // 4,194,304
    const size_t MM   = (size_t)DM * DM;       // 1,048,576
    const int    M    = 2 * LQ;                // 4096
    const float  QSCL = 0.125f * LOG2E;        // 1/sqrt(dk) * log2(e): exp2-domain softmax

    __hip_bfloat16* Qb  = (__hip_bfloat16*)d_ws;
    __hip_bfloat16* Kb  = Qb + NTOK;
    __hip_bfloat16* Vtb = Kb + NTOK;           // transposed V: [b][h][64][2048]
    __hip_bfloat16* Ab  = Vtb + NTOK;

    const size_t need = (4 * NTOK + 2 * NTOK + 4 * MM) * sizeof(__hip_bfloat16);
    const dim3 agrid(512, 1, 1);  // flat, XCD-clustered decode in-kernel

    if (ws_size >= need) {
        __hip_bfloat16* xb  = Ab + NTOK;
        __hip_bfloat16* yb  = xb + NTOK;
        __hip_bfloat16* Wqt = yb + NTOK;
        __hip_bfloat16* Wkt = Wqt + MM;   // [Wqt; Wkt; Wvt] contiguous = stacked QKV B
        __hip_bfloat16* Wvt = Wkt + MM;
        __hip_bfloat16* Wot = Wvt + MM;
        (void)Wkt; (void)Wvt;

        prep_all<<<5120, 256, 0, stream>>>(x, y, Wq, Wk, Wv, Wo,
                                           xb, yb, Wqt, Wkt, Wvt, Wot);

        gemm_qkv<<<192, 512, 0, stream>>>(xb, yb, Wqt, bq, bk, bv, Qb, Kb, Vtb, QSCL);
        attn_mfma11<<<agrid, 256, 0, stream>>>(Qb, Kb, Vtb, Ab);
        gemm_o<<<512, 256, 0, stream>>>(Ab, Wot, bo, (float*)d_out, M);
    } else {
        const dim3 gblk(DM / 64, M / 64);
        gemm64<true,  false><<<gblk, 256, 0, stream>>>(x, Wq, bq, Qb, M, DM, DM, QSCL);
        gemm64<true,  false><<<gblk, 256, 0, stream>>>(y, Wk, bk, Kb, M, DM, DM, 1.0f);
        gemm64<true,  false, true><<<gblk, 256, 0, stream>>>(y, Wv, bv, Vtb, M, DM, DM, 1.0f);
        attn_mfma11<<<agrid, 256, 0, stream>>>(Qb, Kb, Vtb, Ab);
        gemm64<false, true ><<<gblk, 256, 0, stream>>>(Ab, Wo, bo, (float*)d_out, M, DM, DM, 1.0f);
    }
}

// Round 12
// 208.850 us; speedup vs baseline: 1.0882x; 1.0216x over previous
//
#include <hip/hip_runtime.h>
#include <hip/hip_bf16.h>

typedef __attribute__((ext_vector_type(8))) short short8;   // 8 bf16 = 4 VGPRs (MFMA A/B frag)
typedef __attribute__((ext_vector_type(4))) float floatx4;  // MFMA C/D frag

#define LQ 2048
#define DM 1024
#define NH 16
#define LOG2E 1.44269504088896f

typedef __attribute__((address_space(1))) void gas_t;
typedef __attribute__((address_space(3))) void las_t;

// async global->LDS, 16B per lane; LDS dest = wave-uniform base + lane*16
__device__ __forceinline__ void async16(const __hip_bfloat16* g, __hip_bfloat16* l) {
    __builtin_amdgcn_global_load_lds((gas_t*)g, (las_t*)l, 16, 0, 0);
}

// ---------------------------------------------------------------------------
// Fused prep: blocks [0,2048) convert x; [2048,4096) convert y;
// [4096,5120) transpose-convert the 4 weight matrices (64x64 tiles).
// ---------------------------------------------------------------------------
__global__ __launch_bounds__(256) void prep_all(
    const float* __restrict__ x,  const float* __restrict__ y,
    const float* __restrict__ Wq, const float* __restrict__ Wk,
    const float* __restrict__ Wv, const float* __restrict__ Wo,
    __hip_bfloat16* __restrict__ xb,  __hip_bfloat16* __restrict__ yb,
    __hip_bfloat16* __restrict__ Wqt, __hip_bfloat16* __restrict__ Wkt,
    __hip_bfloat16* __restrict__ Wvt, __hip_bfloat16* __restrict__ Wot)
{
    __shared__ float tile[64][65];
    const int t  = threadIdx.x;
    const int bx = blockIdx.x;

    if (bx < 4096) {
        const float* in = (bx < 2048) ? x : y;
        __hip_bfloat16* out = (bx < 2048) ? xb : yb;
        const int i = ((bx & 2047) * 256 + t) * 8;
        float4 a0 = ((const float4*)(in + i))[0];
        float4 a1 = ((const float4*)(in + i))[1];
        union { __hip_bfloat16 h[8]; uint4 u; } pk;
        pk.h[0] = __float2bfloat16(a0.x); pk.h[1] = __float2bfloat16(a0.y);
        pk.h[2] = __float2bfloat16(a0.z); pk.h[3] = __float2bfloat16(a0.w);
        pk.h[4] = __float2bfloat16(a1.x); pk.h[5] = __float2bfloat16(a1.y);
        pk.h[6] = __float2bfloat16(a1.z); pk.h[7] = __float2bfloat16(a1.w);
        *(uint4*)(out + i) = pk.u;
        return;
    }

    const int r    = bx - 4096;       // 0..1023
    const int wsel = r >> 8;          // 0..3
    const int tid  = r & 255;
    const int n0   = (tid & 15) * 64, k0 = (tid >> 4) * 64;
    const float* W = (wsel == 0) ? Wq : (wsel == 1) ? Wk : (wsel == 2) ? Wv : Wo;
    __hip_bfloat16* Wt = (wsel == 0) ? Wqt : (wsel == 1) ? Wkt : (wsel == 2) ? Wvt : Wot;

    const int rr0 = t >> 4, c4 = (t & 15) * 4;
#pragma unroll
    for (int rr = 0; rr < 64; rr += 16) {
        float4 v = *(const float4*)&W[(size_t)(k0 + rr0 + rr) * DM + n0 + c4];
        tile[rr0 + rr][c4 + 0] = v.x; tile[rr0 + rr][c4 + 1] = v.y;
        tile[rr0 + rr][c4 + 2] = v.z; tile[rr0 + rr][c4 + 3] = v.w;
    }
    __syncthreads();
    const int nr = t >> 2, kc = (t & 3) * 16;
    union { __hip_bfloat16 h[16]; uint4 u[2]; } pk;
#pragma unroll
    for (int i = 0; i < 16; ++i) pk.h[i] = __float2bfloat16(tile[kc + i][nr]);
    uint4* dst = (uint4*)&Wt[(size_t)(n0 + nr) * DM + k0 + kc];
    dst[0] = pk.u[0];
    dst[1] = pk.u[1];
}

// ---------------------------------------------------------------------------
// Fused QKV GEMM v5: 256x128 tile, 8 waves (4m x 2n, wave tile 64x64),
// 8-phase m201-style schedule, 3 rotating K-half slots (72 KB LDS), grid
// 384 = 8 XCD x (6bx x 8by) -> 2 blocks/CU co-resident (fixes the 192-block
// 25%-idle-CU bug of the 256x256 tiling). 3 loads/thread/half-step (2 A + 1
// B, uniform) -> steady-state vmcnt(3). T2 swizzle as before.
// n in [0,1024)   -> Q; [1024,2048) -> K; [2048,3072) -> V transposed.
// ---------------------------------------------------------------------------
__global__ __launch_bounds__(512, 4) void gemm_qkv(
    const __hip_bfloat16* __restrict__ xb,
    const __hip_bfloat16* __restrict__ yb,
    const __hip_bfloat16* __restrict__ Bt,   // Wqt (Wkt, Wvt contiguous after)
    const float* __restrict__ bq, const float* __restrict__ bk,
    const float* __restrict__ bv,
    __hip_bfloat16* __restrict__ Qb, __hip_bfloat16* __restrict__ Kb,
    __hip_bfloat16* __restrict__ Vt,
    float qscl)
{
    constexpr int BM = 256, BN = 128, Kd = 1024;
    constexpr int NHS = Kd / 32;                 // 32 K-half steps
    __shared__ __align__(16) __hip_bfloat16 As[3][BM * 32];  // 3 x 16 KB
    __shared__ __align__(16) __hip_bfloat16 Bs[3][BN * 32];  // 3 x 8 KB

    const int t    = threadIdx.x;
    const int w    = t >> 6;        // 0..7
    const int lane = t & 63;
    const int quad = lane >> 4;
    const int l16  = lane & 15;
    const int wm   = w & 3;         // 4 m-groups of 64 rows
    const int wn   = w >> 2;        // 2 n-groups of 64 cols

    // XCD-rect decode: 384 = 8 XCD x (6bx x 8by); n-tiles 24, m-tiles 16
    const int f  = blockIdx.x;
    const int rx = f & 7;
    const int rr = f >> 3;               // 0..47
    const int bx = (rx & 3) * 6 + rr % 6;
    const int by = (rx >> 2) * 8 + rr / 6;
    const int m0 = by * BM;
    const int n0 = bx * BN;

    const int region = n0 >> 10;             // 0=Q 1=K 2=V (block-uniform; 128|1024)
    const int nl     = n0 & 1023;

    const __hip_bfloat16* A = (region == 0) ? xb : yb;

    floatx4 acc[4][4];
#pragma unroll
    for (int i = 0; i < 4; ++i)
#pragma unroll
        for (int j = 0; j < 4; ++j) acc[i][j] = (floatx4){0.f, 0.f, 0.f, 0.f};

    // A half-step: 256x32 bf16 = 16 KB = 1024 chunks -> 2 chunks/thread.
    // B half-step: 128x32 bf16 =  8 KB =  512 chunks -> 1 chunk/thread.
    // Source pre-swizzled: physical chunk c holds logical (c&3)^((row>>1)&3).
    auto stageA = [&](int h) {
        const int k0 = h * 32, slot = h % 3;
#pragma unroll
        for (int l = 0; l < 2; ++l) {
            const int c   = l * 512 + t;
            const int row = c >> 2;
            const int ch  = (c & 3) ^ ((row >> 1) & 3);
            async16(A + (size_t)(m0 + row) * Kd + k0 + ch * 8, &As[slot][c * 8]);
        }
    };
    auto stageB = [&](int h) {
        const int k0 = h * 32, slot = h % 3;
        const int c   = t;
        const int row = c >> 2;
        const int ch  = (c & 3) ^ ((row >> 1) & 3);
        async16(Bt + (size_t)(n0 + row) * Kd + k0 + ch * 8, &Bs[slot][c * 8]);
    };

    // prologue: half-steps 0 and 1 in flight (6 loads/thr); retire h=0's 3
    stageA(0); stageB(0); stageA(1); stageB(1);
    asm volatile("s_waitcnt vmcnt(3)" ::: "memory");
    __builtin_amdgcn_sched_barrier(0);
    __builtin_amdgcn_s_barrier();

    const int csw = (l16 >> 1) & 3;   // read-side chunk swizzle (== (row>>1)&3)

    for (int h = 0; h < NHS; ++h) {
        const int slot = h % 3;
        const __hip_bfloat16* as = &As[slot][0];
        const __hip_bfloat16* bs = &Bs[slot][0];
        short8 af[4], bf[4];

        // ---- phase A: bf[0..3] + af[0..1], stage A(h+2), 8 MFMA ----
#pragma unroll
        for (int nj = 0; nj < 4; ++nj) {
            const int row = wn * 64 + nj * 16 + l16;
            bf[nj] = *(const short8*)&bs[row * 32 + (quad ^ csw) * 8];
        }
#pragma unroll
        for (int mi = 0; mi < 2; ++mi) {
            const int row = wm * 64 + mi * 16 + l16;
            af[mi] = *(const short8*)&as[row * 32 + (quad ^ csw) * 8];
        }
        if (h + 2 < NHS) stageA(h + 2);
        __builtin_amdgcn_s_barrier();
        asm volatile("s_waitcnt lgkmcnt(0)" ::: "memory");
        __builtin_amdgcn_sched_barrier(0);
        __builtin_amdgcn_s_setprio(1);
#pragma unroll
        for (int mi = 0; mi < 2; ++mi)
#pragma unroll
            for (int nj = 0; nj < 4; ++nj)
                acc[mi][nj] = __builtin_amdgcn_mfma_f32_16x16x32_bf16(af[mi], bf[nj], acc[mi][nj], 0, 0, 0);
        __builtin_amdgcn_s_setprio(0);
        __builtin_amdgcn_s_barrier();

        // ---- phase B: af[2..3], stage B(h+2), 8 MFMA, counted vmcnt ----
#pragma unroll
        for (int mi = 2; mi < 4; ++mi) {
            const int row = wm * 64 + mi * 16 + l16;
            af[mi] = *(const short8*)&as[row * 32 + (quad ^ csw) * 8];
        }
        if (h + 2 < NHS) stageB(h + 2);
        __builtin_amdgcn_s_barrier();
        asm volatile("s_waitcnt lgkmcnt(0)" ::: "memory");
        __builtin_amdgcn_sched_barrier(0);
        __builtin_amdgcn_s_setprio(1);
#pragma unroll
        for (int mi = 2; mi < 4; ++mi)
#pragma unroll
            for (int nj = 0; nj < 4; ++nj)
                acc[mi][nj] = __builtin_amdgcn_mfma_f32_16x16x32_bf16(af[mi], bf[nj], acc[mi][nj], 0, 0, 0);
        __builtin_amdgcn_s_setprio(0);
        // retire half-step h+1's 3 loads (leave h+2's in flight); tail drains
        if (h + 2 < NHS)      asm volatile("s_waitcnt vmcnt(3)" ::: "memory");
        else                  asm volatile("s_waitcnt vmcnt(0)" ::: "memory");
        __builtin_amdgcn_sched_barrier(0);
        __builtin_amdgcn_s_barrier();
    }

    if (region < 2) {
        __hip_bfloat16* C    = (region == 0) ? Qb : Kb;
        const float*    bias = (region == 0) ? bq : bk;
        const float     scl  = (region == 0) ? qscl : 1.0f;
#pragma unroll
        for (int j = 0; j < 4; ++j) {
            const int col = nl + wn * 64 + j * 16 + l16;
            const float bvv = bias[col];
#pragma unroll
            for (int mi = 0; mi < 4; ++mi) {
#pragma unroll
                for (int r = 0; r < 4; ++r) {
                    const int row = m0 + wm * 64 + mi * 16 + quad * 4 + r;
                    C[(size_t)row * 1024 + col] = __float2bfloat16((acc[mi][j][r] + bvv) * scl);
                }
            }
        }
    } else {
        // V transposed per head: addr = (b*1024 + col)*2048 + j.
#pragma unroll
        for (int j = 0; j < 4; ++j) {
            const int col = nl + wn * 64 + j * 16 + l16;
            const float bvv = bv[col];
#pragma unroll
            for (int mi = 0; mi < 4; ++mi) {
                const int row0 = m0 + wm * 64 + mi * 16 + quad * 4;
                union { __hip_bfloat16 h4[4]; uint2 u; } pk;
#pragma unroll
                for (int r = 0; r < 4; ++r)
                    pk.h4[r] = __float2bfloat16(acc[mi][j][r] + bvv);
                *(uint2*)&Vt[((size_t)((row0 >> 11) * 1024 + col)) * 2048 + (row0 & 2047)] = pk.u;
            }
        }
    }
}

// ---------------------------------------------------------------------------
// O-projection GEMM: 64x128 tile, XCD-rect, f32 out; 3-buffer depth-2
// counted-vmcnt pipeline (3 async16/stage -> vmcnt(3|0)).
// ---------------------------------------------------------------------------
__global__ __launch_bounds__(256) void gemm_o(
    const __hip_bfloat16* __restrict__ A,    // [M,1024]
    const __hip_bfloat16* __restrict__ Bt,   // [1024,1024] (Wot)
    const float* __restrict__ bias,
    float* __restrict__ C,                   // [M,1024] f32
    int M)
{
    constexpr int BM = 64, BN = 128, BK = 32, Kd = 1024, NIT = Kd / BK;
    __shared__ __align__(16) __hip_bfloat16 As[3][BM * BK];  // 3 x 4 KB
    __shared__ __align__(16) __hip_bfloat16 Bs[3][BN * BK];  // 3 x 8 KB

    const int t    = threadIdx.x;
    const int w    = t >> 6;
    const int lane = t & 63;
    const int quad = lane >> 4;
    const int l16  = lane & 15;
    const int wm   = w & 1;         // 2 m-halves of 32 rows
    const int wn   = w >> 1;        // 2 n-halves of 64 cols

    // XCD-rect decode: 512 = 8 XCD x (4bx x 16by)
    const int f  = blockIdx.x;
    const int rx = f & 7;
    const int rr = f >> 3;               // 0..63
    const int bx = (rx & 1) * 4 + (rr & 3);
    const int by = (rx >> 1) * 16 + (rr >> 2);
    const int m0 = by * BM;
    const int n0 = bx * BN;

    const int lrow = lane >> 2;
    const int lcol = (lane & 3) * 8;

    floatx4 acc[2][4];
#pragma unroll
    for (int i = 0; i < 2; ++i)
#pragma unroll
        for (int j = 0; j < 4; ++j) acc[i][j] = (floatx4){0.f, 0.f, 0.f, 0.f};

    // 12 segments (4 A + 8 B), 3 per wave
    auto stage = [&](int k0, int buf) {
#pragma unroll
        for (int s = 0; s < 3; ++s) {
            const int seg = w * 3 + s;
            if (seg < 4) {
                async16(A + (size_t)(m0 + seg * 16 + lrow) * Kd + k0 + lcol,
                        &As[buf][seg * 16 * BK]);
            } else {
                const int bs = seg - 4;
                async16(Bt + (size_t)(n0 + bs * 16 + lrow) * Kd + k0 + lcol,
                        &Bs[buf][bs * 16 * BK]);
            }
        }
    };

    stage(0, 0);
    stage(BK, 1);
    int cur = 0;
    for (int i = 0; i < NIT; ++i) {
        if (i < NIT - 1) asm volatile("s_waitcnt vmcnt(3)" ::: "memory");
        else             asm volatile("s_waitcnt vmcnt(0)" ::: "memory");
        __builtin_amdgcn_sched_barrier(0);
        __builtin_amdgcn_s_barrier();
        if (i + 2 < NIT) stage((i + 2) * BK, (cur + 2 >= 3) ? cur - 1 : cur + 2);

        short8 af[2], bf[4];
#pragma unroll
        for (int ii = 0; ii < 2; ++ii)
            af[ii] = *(const short8*)&As[cur][(wm * 32 + ii * 16 + l16) * BK + quad * 8];
#pragma unroll
        for (int j = 0; j < 4; ++j)
            bf[j] = *(const short8*)&Bs[cur][(wn * 64 + j * 16 + l16) * BK + quad * 8];
#pragma unroll
        for (int ii = 0; ii < 2; ++ii)
#pragma unroll
            for (int j = 0; j < 4; ++j)
                acc[ii][j] = __builtin_amdgcn_mfma_f32_16x16x32_bf16(af[ii], bf[j], acc[ii][j], 0, 0, 0);
        cur = (cur + 1 >= 3) ? 0 : cur + 1;
    }

#pragma unroll
    for (int j = 0; j < 4; ++j) {
        const int col = n0 + wn * 64 + j * 16 + l16;
        const float bvf = bias[col];
#pragma unroll
        for (int i = 0; i < 2; ++i) {
#pragma unroll
            for (int r = 0; r < 4; ++r) {
                const int row = m0 + wm * 32 + i * 16 + quad * 4 + r;
                C[(size_t)row * 1024 + col] = acc[i][j][r] + bvf;
            }
        }
    }
}

// ---------------------------------------------------------------------------
// Fallback GEMM (fp32 inputs, fused convert, 64x64 tile). TRANSV writes the
// output per-head-transposed into Vt layout.
// ---------------------------------------------------------------------------
template <bool A_IS_F32, bool OUT_F32, bool TRANSV = false>
__global__ __launch_bounds__(256) void gemm64(
    const void* __restrict__ Av,
    const float* __restrict__ B,
    const float* __restrict__ bias,
    void* __restrict__ Cv,
    int M, int N, int K, float scale)
{
    __shared__ __align__(16) __hip_bfloat16 As[64][40];
    __shared__ __align__(16) __hip_bfloat16 Bs[64][40];

    const int t    = threadIdx.x;
    const int wave = t >> 6;
    const int lane = t & 63;
    const int quad = lane >> 4;
    const int l16  = lane & 15;
    const int m0   = blockIdx.y * 64;
    const int n0   = blockIdx.x * 64;

    floatx4 acc[4];
#pragma unroll
    for (int i = 0; i < 4; ++i) acc[i] = (floatx4){0.f, 0.f, 0.f, 0.f};

    const int arow = t >> 2, acol = (t & 3) * 8;
    const int bkk  = t >> 3, bnn  = (t & 7) * 8;

    for (int k0 = 0; k0 < K; k0 += 32) {
        if constexpr (A_IS_F32) {
            const float* A = (const float*)Av;
            const float* ap = A + (size_t)(m0 + arow) * K + k0 + acol;
            float4 a0 = ((const float4*)ap)[0];
            float4 a1 = ((const float4*)ap)[1];
            union { __hip_bfloat16 h[8]; short8 s; } up;
            up.h[0] = __float2bfloat16(a0.x); up.h[1] = __float2bfloat16(a0.y);
            up.h[2] = __float2bfloat16(a0.z); up.h[3] = __float2bfloat16(a0.w);
            up.h[4] = __float2bfloat16(a1.x); up.h[5] = __float2bfloat16(a1.y);
            up.h[6] = __float2bfloat16(a1.z); up.h[7] = __float2bfloat16(a1.w);
            *(short8*)(&As[arow][acol]) = up.s;
        } else {
            const __hip_bfloat16* A = (const __hip_bfloat16*)Av;
            uint4 av = *(const uint4*)(A + (size_t)(m0 + arow) * K + k0 + acol);
            *(uint4*)(&As[arow][acol]) = av;
        }
        {
            const float* bp = B + (size_t)(k0 + bkk) * N + n0 + bnn;
            float4 b0 = ((const float4*)bp)[0];
            float4 b1 = ((const float4*)bp)[1];
            Bs[bnn + 0][bkk] = __float2bfloat16(b0.x);
            Bs[bnn + 1][bkk] = __float2bfloat16(b0.y);
            Bs[bnn + 2][bkk] = __float2bfloat16(b0.z);
            Bs[bnn + 3][bkk] = __float2bfloat16(b0.w);
            Bs[bnn + 4][bkk] = __float2bfloat16(b1.x);
            Bs[bnn + 5][bkk] = __float2bfloat16(b1.y);
            Bs[bnn + 6][bkk] = __float2bfloat16(b1.z);
            Bs[bnn + 7][bkk] = __float2bfloat16(b1.w);
        }
        __syncthreads();

        short8 afrag = *(const short8*)(&As[wave * 16 + l16][quad * 8]);
#pragma unroll
        for (int nt = 0; nt < 4; ++nt) {
            short8 bfrag = *(const short8*)(&Bs[nt * 16 + l16][quad * 8]);
            acc[nt] = __builtin_amdgcn_mfma_f32_16x16x32_bf16(afrag, bfrag, acc[nt], 0, 0, 0);
        }
        __syncthreads();
    }

#pragma unroll
    for (int nt = 0; nt < 4; ++nt) {
        const int col = n0 + nt * 16 + l16;
        const float bvf = bias[col];
        if constexpr (TRANSV) {
            const int row0 = m0 + wave * 16 + quad * 4;
            union { __hip_bfloat16 h4[4]; uint2 u; } pk;
#pragma unroll
            for (int r = 0; r < 4; ++r)
                pk.h4[r] = __float2bfloat16(acc[nt][r] + bvf);
            *(uint2*)&((__hip_bfloat16*)Cv)[((size_t)((row0 >> 11) * 1024 + col)) * 2048 + (row0 & 2047)] = pk.u;
        } else {
#pragma unroll
            for (int r = 0; r < 4; ++r) {
                const int row = m0 + wave * 16 + quad * 4 + r;
                const float v = (acc[nt][r] + bvf) * scale;
                if constexpr (OUT_F32) ((float*)Cv)[(size_t)row * N + col] = v;
                else ((__hip_bfloat16*)Cv)[(size_t)row * N + col] = __float2bfloat16(v);
            }
        }
    }
}

// ---------------------------------------------------------------------------
// MFMA flash attention v11 (round-11 proven, unchanged): T15 2-tile pipeline
// (PV of jt-1 overlaps K(jt) reads), V 4 slots / K 3 slots, counted vmcnt,
// race-safe post-barrier staging, XCD-clustered + causal balance pairing.
// ---------------------------------------------------------------------------
#define PP 72                 // P/Q row pitch (144 B = 9*16B, aligned)

__global__ __launch_bounds__(256, 2) void attn_mfma11(
    const __hip_bfloat16* __restrict__ Q,
    const __hip_bfloat16* __restrict__ K,
    const __hip_bfloat16* __restrict__ Vt,   // [b][h][64 d][2048 j]
    __hip_bfloat16* __restrict__ O)
{
    __shared__ __align__(16) __hip_bfloat16 KtS[3][64 * 64];  // 24 KB, swizzled rows
    __shared__ __align__(16) __hip_bfloat16 VtS[4][64 * 64];  // 32 KB, swizzled rows
    __shared__ __align__(16) __hip_bfloat16 PsQ[128 * PP];    // 18 KB: Q stage, then per-wave P

    const int t    = threadIdx.x;
    const int w    = t >> 6;
    const int lane = t & 63;
    const int quad = lane >> 4;
    const int l16  = lane & 15;

    // XCD-clustered + balance-paired decode
    const int f   = blockIdx.x;
    const int xcd = f & 7;
    const int u   = f >> 3;        // 0..63
    const int pi  = u >> 4;        // 0..3 (pair index within XCD)
    const int qr  = u & 15;
    const int qx  = (pi & 2) ? (15 - qr) : qr;   // second round flips -> 34 iters/CU
    const int p   = xcd * 4 + pi;  // (b,h) pair 0..31
    const int h   = p & 15;
    const int b   = p >> 4;
    const int q0  = qx * 128;

    const size_t rowbase = (size_t)b * LQ;
    const int    hcol    = h * 64;
    const size_t vbase   = (size_t)(b * NH + h) * 64 * LQ;

    const int r8 = l16 & 7;

    // stage K (slot jt%3) and V^T (slot jt&3) 64x64 tiles; pre-swizzled
    // global source, linear LDS dest. 4 async16/thread per stage.
    auto stage = [&](int j0n, int jtile) {
        const int ks = jtile % 3;
        const int vs = jtile & 3;
#pragma unroll
        for (int rnd = 0; rnd < 2; ++rnd) {
            const int c   = rnd * 256 + t;          // 16B chunk index, 0..511
            const int row = c >> 3;                 // 0..63
            const int ch  = (c & 7) ^ (row & 7);    // swizzled source chunk
            async16(K + (rowbase + j0n + row) * DM + hcol + ch * 8,
                    &KtS[ks][c * 8]);
            async16(Vt + vbase + (size_t)row * LQ + j0n + ch * 8,
                    &VtS[vs][c * 8]);
        }
    };

    // ---- Q tile (128 rows x 64) -> LDS (wave-local rows: no barrier) ----
    {
        const int qrow = t >> 1, qseg = (t & 1) * 32;   // 64B per thread
        const uint4* src = (const uint4*)(Q + (rowbase + q0 + qrow) * DM + hcol + qseg);
        uint4* dst = (uint4*)&PsQ[qrow * PP + qseg];
        dst[0] = src[0]; dst[1] = src[1]; dst[2] = src[2]; dst[3] = src[3];
    }
    stage(0, 0);
    stage(64, 1);

    // qf reads own wave's rows (ordered vs own stores by lgkmcnt)
    short8 qf[2][2];
#pragma unroll
    for (int g = 0; g < 2; ++g)
#pragma unroll
        for (int hh = 0; hh < 2; ++hh)
            qf[g][hh] = *(const short8*)&PsQ[(w * 32 + g * 16 + l16) * PP + hh * 32 + quad * 8];

    __hip_bfloat16* Pw = &PsQ[(w * 32) * PP];  // wave-private P[32 q][64 j]

    float l_i[2] = {0.f, 0.f};
    floatx4 o[2][4];
#pragma unroll
    for (int g = 0; g < 2; ++g)
#pragma unroll
        for (int i = 0; i < 4; ++i) o[g][i] = (floatx4){0.f, 0.f, 0.f, 0.f};

    const int wq_lo  = q0 + w * 32;       // first q row of this wave
    const int wq_hi  = wq_lo + 31;
    const int ntiles = 2 * qx + 2;

    short8 pa[2][2];          // P fragments of the PREVIOUS tile (persist)
    int    pslot = -1;        // V slot of the previous tile; -1 = none

    for (int jt = 0; jt < ntiles; ++jt) {
        const int j0 = jt * 64;

        // retire own stage(jt) (4 loads), keep stage(jt+1) in flight
        if (jt < ntiles - 1) asm volatile("s_waitcnt vmcnt(4)" ::: "memory");
        else                 asm volatile("s_waitcnt vmcnt(0)" ::: "memory");
        __builtin_amdgcn_sched_barrier(0);
        __builtin_amdgcn_s_barrier();
        // safe: K slot (jt+2)%3 and V slot (jt+2)&3 retired by the barrier
        if (jt + 2 < ntiles) stage(j0 + 128, jt + 2);

        const bool active = (j0 <= wq_hi);

        // ---- issue K(jt) fragment reads early (overlap with PV below) ----
        short8 ak[4][2];
        if (active) {
#pragma unroll
            for (int jc = 0; jc < 4; ++jc) {
                const __hip_bfloat16* kr = &KtS[jt % 3][(jc * 16 + l16) * 64];
                ak[jc][0] = *(const short8*)&kr[((quad    ) ^ r8) * 8];
                ak[jc][1] = *(const short8*)&kr[((quad + 4) ^ r8) * 8];
            }
        }

        // ---- PV of PREVIOUS tile (pure MFMA; hides K ds_read latency) ----
        if (pslot >= 0) {
            __builtin_amdgcn_s_setprio(1);
#pragma unroll
            for (int subf = 0; subf < 4; ++subf) {
                const __hip_bfloat16* vr = &VtS[pslot][(subf * 16 + l16) * 64];
                short8 vb0 = *(const short8*)&vr[((quad    ) ^ r8) * 8];
                short8 vb1 = *(const short8*)&vr[((quad + 4) ^ r8) * 8];
#pragma unroll
                for (int g = 0; g < 2; ++g) {
                    o[g][subf] = __builtin_amdgcn_mfma_f32_16x16x32_bf16(pa[g][0], vb0, o[g][subf], 0, 0, 0);
                    o[g][subf] = __builtin_amdgcn_mfma_f32_16x16x32_bf16(pa[g][1], vb1, o[g][subf], 0, 0, 0);
                }
            }
            __builtin_amdgcn_s_setprio(0);
            pslot = -1;
        }

        if (active) {
            const bool bnd = (j0 + 63 > wq_lo);   // boundary: needs causal mask
            // ---- S^T = K * Q^T, fused softmax numerator per (g, jc) ----
            __builtin_amdgcn_s_setprio(1);
#pragma unroll
            for (int jc = 0; jc < 4; ++jc) {
#pragma unroll
                for (int g = 0; g < 2; ++g) {
                    floatx4 z = (floatx4){0.f, 0.f, 0.f, 0.f};
                    z = __builtin_amdgcn_mfma_f32_16x16x32_bf16(ak[jc][0], qf[g][0], z, 0, 0, 0);
                    z = __builtin_amdgcn_mfma_f32_16x16x32_bf16(ak[jc][1], qf[g][1], z, 0, 0, 0);
                    if (bnd) {
                        const int qg = wq_lo + g * 16 + l16;
#pragma unroll
                        for (int r = 0; r < 4; ++r) {
                            const int j = j0 + jc * 16 + quad * 4 + r;
                            if (j > qg) z[r] = -1e30f;
                        }
                    }
                    union { __hip_bfloat16 h4[4]; uint2 u; } pk;
#pragma unroll
                    for (int r = 0; r < 4; ++r) {
                        const float e = __builtin_amdgcn_exp2f(z[r]);
                        l_i[g] += e;
                        pk.h4[r] = __float2bfloat16(e);
                    }
                    *(uint2*)&Pw[(g * 16 + l16) * PP + jc * 16 + quad * 4] = pk.u;
                }
            }
            __builtin_amdgcn_s_setprio(0);
            // ---- P frags for NEXT iter's PV (wave-local write->read) ----
#pragma unroll
            for (int g = 0; g < 2; ++g) {
                pa[g][0] = *(const short8*)&Pw[(g * 16 + l16) * PP + quad * 8];
                pa[g][1] = *(const short8*)&Pw[(g * 16 + l16) * PP + 32 + quad * 8];
            }
            pslot = jt & 3;
        }
    }

    // ---- flush final PV (V slot of the last active tile is not reused) ----
    if (pslot >= 0) {
#pragma unroll
        for (int subf = 0; subf < 4; ++subf) {
            const __hip_bfloat16* vr = &VtS[pslot][(subf * 16 + l16) * 64];
            short8 vb0 = *(const short8*)&vr[((quad    ) ^ r8) * 8];
            short8 vb1 = *(const short8*)&vr[((quad + 4) ^ r8) * 8];
#pragma unroll
            for (int g = 0; g < 2; ++g) {
                o[g][subf] = __builtin_amdgcn_mfma_f32_16x16x32_bf16(pa[g][0], vb0, o[g][subf], 0, 0, 0);
                o[g][subf] = __builtin_amdgcn_mfma_f32_16x16x32_bf16(pa[g][1], vb1, o[g][subf], 0, 0, 0);
            }
        }
    }

#pragma unroll
    for (int g = 0; g < 2; ++g) {
        l_i[g] += __shfl_xor(l_i[g], 16);
        l_i[g] += __shfl_xor(l_i[g], 32);
#pragma unroll
        for (int r = 0; r < 4; ++r) {
            const float linv = 1.0f / __shfl(l_i[g], quad * 4 + r);
            const size_t row = rowbase + q0 + w * 32 + g * 16 + quad * 4 + r;
#pragma unroll
            for (int subf = 0; subf < 4; ++subf)
                O[row * DM + hcol + subf * 16 + l16] = __float2bfloat16(o[g][subf][r] * linv);
        }
    }
}

// ---------------------------------------------------------------------------
extern "C" void kernel_launch(void* const* d_in, const int* in_sizes, int n_in,
                              void* d_out, int out_size, void* d_ws, size_t ws_size,
                              hipStream_t stream)
{
    (void)in_sizes; (void)n_in; (void)out_size;

    const float* x  = (const float*)d_in[0];
    const float* y  = (const float*)d_in[1];
    // d_in[2] = mask: causal tril, handled analytically
    const float* Wq = (const float*)d_in[3];
    const float* bq = (const float*)d_in[4];
    const float* Wk = (const float*)d_in[5];
    const float* bk = (const float*)d_in[6];
    const float* Wv = (const float*)d_in[7];
    const float* bv = (const float*)d_in[8];
    const float* Wo = (const float*)d_in[9];
    const float* bo = (const float*)d_in[10];

    const size_t NTOK = (size_t)2 * LQ * DM;   // 4,194,304
    const size_t MM   = (size_t)DM * DM;       // 1,048,576
    const int    M    = 2 * LQ;                // 4096
    const float  QSCL = 0.125f * LOG2E;        // 1/sqrt(dk) * log2(e): exp2-domain softmax

    __hip_bfloat16* Qb  = (__hip_bfloat16*)d_ws;
    __hip_bfloat16* Kb  = Qb + NTOK;
    __hip_bfloat16* Vtb = Kb + NTOK;           // transposed V: [b][h][64][2048]
    __hip_bfloat16* Ab  = Vtb + NTOK;

    const size_t need = (4 * NTOK + 2 * NTOK + 4 * MM) * sizeof(__hip_bfloat16);
    const dim3 agrid(512, 1, 1);  // flat, XCD-clustered decode in-kernel

    if (ws_size >= need) {
        __hip_bfloat16* xb  = Ab + NTOK;
        __hip_bfloat16* yb  = xb + NTOK;
        __hip_bfloat16* Wqt = yb + NTOK;
        __hip_bfloat16* Wkt = Wqt + MM;   // [Wqt; Wkt; Wvt] contiguous = stacked QKV B
        __hip_bfloat16* Wvt = Wkt + MM;
        __hip_bfloat16* Wot = Wvt + MM;
        (void)Wkt; (void)Wvt;

        prep_all<<<5120, 256, 0, stream>>>(x, y, Wq, Wk, Wv, Wo,
                                           xb, yb, Wqt, Wkt, Wvt, Wot);

        gemm_qkv<<<384, 512, 0, stream>>>(xb, yb, Wqt, bq, bk, bv, Qb, Kb, Vtb, QSCL);
        attn_mfma11<<<agrid, 256, 0, stream>>>(Qb, Kb, Vtb, Ab);
        gemm_o<<<512, 256, 0, stream>>>(Ab, Wot, bo, (float*)d_out, M);
    } else {
        const dim3 gblk(DM / 64, M / 64);
        gemm64<true,  false><<<gblk, 256, 0, stream>>>(x, Wq, bq, Qb, M, DM, DM, QSCL);
        gemm64<true,  false><<<gblk, 256, 0, stream>>>(y, Wk, bk, Kb, M, DM, DM, 1.0f);
        gemm64<true,  false, true><<<gblk, 256, 0, stream>>>(y, Wv, bv, Vtb, M, DM, DM, 1.0f);
        attn_mfma11<<<agrid, 256, 0, stream>>>(Qb, Kb, Vtb, Ab);
        gemm64<false, true ><<<gblk, 256, 0, stream>>>(Ab, Wo, bo, (float*)d_out, M, DM, DM, 1.0f);
    }
}

// Round 13
// 201.665 us; speedup vs baseline: 1.1269x; 1.0356x over previous
//
#include <hip/hip_runtime.h>
#include <hip/hip_bf16.h>

typedef __attribute__((ext_vector_type(8))) short short8;   // 8 bf16 = 4 VGPRs (MFMA A/B frag)
typedef __attribute__((ext_vector_type(4))) float floatx4;  // MFMA C/D frag

#define LQ 2048
#define DM 1024
#define NH 16
#define LOG2E 1.44269504088896f

typedef __attribute__((address_space(1))) void gas_t;
typedef __attribute__((address_space(3))) void las_t;

// async global->LDS, 16B per lane; LDS dest = wave-uniform base + lane*16
__device__ __forceinline__ void async16(const __hip_bfloat16* g, __hip_bfloat16* l) {
    __builtin_amdgcn_global_load_lds((gas_t*)g, (las_t*)l, 16, 0, 0);
}

// ---------------------------------------------------------------------------
// Fused prep: blocks [0,2048) convert x; [2048,4096) convert y;
// [4096,5120) transpose-convert the 4 weight matrices (64x64 tiles).
// ---------------------------------------------------------------------------
__global__ __launch_bounds__(256) void prep_all(
    const float* __restrict__ x,  const float* __restrict__ y,
    const float* __restrict__ Wq, const float* __restrict__ Wk,
    const float* __restrict__ Wv, const float* __restrict__ Wo,
    __hip_bfloat16* __restrict__ xb,  __hip_bfloat16* __restrict__ yb,
    __hip_bfloat16* __restrict__ Wqt, __hip_bfloat16* __restrict__ Wkt,
    __hip_bfloat16* __restrict__ Wvt, __hip_bfloat16* __restrict__ Wot)
{
    __shared__ float tile[64][65];
    const int t  = threadIdx.x;
    const int bx = blockIdx.x;

    if (bx < 4096) {
        const float* in = (bx < 2048) ? x : y;
        __hip_bfloat16* out = (bx < 2048) ? xb : yb;
        const int i = ((bx & 2047) * 256 + t) * 8;
        float4 a0 = ((const float4*)(in + i))[0];
        float4 a1 = ((const float4*)(in + i))[1];
        union { __hip_bfloat16 h[8]; uint4 u; } pk;
        pk.h[0] = __float2bfloat16(a0.x); pk.h[1] = __float2bfloat16(a0.y);
        pk.h[2] = __float2bfloat16(a0.z); pk.h[3] = __float2bfloat16(a0.w);
        pk.h[4] = __float2bfloat16(a1.x); pk.h[5] = __float2bfloat16(a1.y);
        pk.h[6] = __float2bfloat16(a1.z); pk.h[7] = __float2bfloat16(a1.w);
        *(uint4*)(out + i) = pk.u;
        return;
    }

    const int r    = bx - 4096;       // 0..1023
    const int wsel = r >> 8;          // 0..3
    const int tid  = r & 255;
    const int n0   = (tid & 15) * 64, k0 = (tid >> 4) * 64;
    const float* W = (wsel == 0) ? Wq : (wsel == 1) ? Wk : (wsel == 2) ? Wv : Wo;
    __hip_bfloat16* Wt = (wsel == 0) ? Wqt : (wsel == 1) ? Wkt : (wsel == 2) ? Wvt : Wot;

    const int rr0 = t >> 4, c4 = (t & 15) * 4;
#pragma unroll
    for (int rr = 0; rr < 64; rr += 16) {
        float4 v = *(const float4*)&W[(size_t)(k0 + rr0 + rr) * DM + n0 + c4];
        tile[rr0 + rr][c4 + 0] = v.x; tile[rr0 + rr][c4 + 1] = v.y;
        tile[rr0 + rr][c4 + 2] = v.z; tile[rr0 + rr][c4 + 3] = v.w;
    }
    __syncthreads();
    const int nr = t >> 2, kc = (t & 3) * 16;
    union { __hip_bfloat16 h[16]; uint4 u[2]; } pk;
#pragma unroll
    for (int i = 0; i < 16; ++i) pk.h[i] = __float2bfloat16(tile[kc + i][nr]);
    uint4* dst = (uint4*)&Wt[(size_t)(n0 + nr) * DM + k0 + kc];
    dst[0] = pk.u[0];
    dst[1] = pk.u[1];
}

// ---------------------------------------------------------------------------
// Fused QKV GEMM v5 (round-12 proven, unchanged): 256x128 tile, 8 waves,
// 8-phase schedule, 3 rotating K-half slots, grid 384 -> 2 blocks/CU.
// ---------------------------------------------------------------------------
__global__ __launch_bounds__(512, 4) void gemm_qkv(
    const __hip_bfloat16* __restrict__ xb,
    const __hip_bfloat16* __restrict__ yb,
    const __hip_bfloat16* __restrict__ Bt,   // Wqt (Wkt, Wvt contiguous after)
    const float* __restrict__ bq, const float* __restrict__ bk,
    const float* __restrict__ bv,
    __hip_bfloat16* __restrict__ Qb, __hip_bfloat16* __restrict__ Kb,
    __hip_bfloat16* __restrict__ Vt,
    float qscl)
{
    constexpr int BM = 256, BN = 128, Kd = 1024;
    constexpr int NHS = Kd / 32;                 // 32 K-half steps
    __shared__ __align__(16) __hip_bfloat16 As[3][BM * 32];  // 3 x 16 KB
    __shared__ __align__(16) __hip_bfloat16 Bs[3][BN * 32];  // 3 x 8 KB

    const int t    = threadIdx.x;
    const int w    = t >> 6;        // 0..7
    const int lane = t & 63;
    const int quad = lane >> 4;
    const int l16  = lane & 15;
    const int wm   = w & 3;         // 4 m-groups of 64 rows
    const int wn   = w >> 2;        // 2 n-groups of 64 cols

    // XCD-rect decode: 384 = 8 XCD x (6bx x 8by); n-tiles 24, m-tiles 16
    const int f  = blockIdx.x;
    const int rx = f & 7;
    const int rr = f >> 3;               // 0..47
    const int bx = (rx & 3) * 6 + rr % 6;
    const int by = (rx >> 2) * 8 + rr / 6;
    const int m0 = by * BM;
    const int n0 = bx * BN;

    const int region = n0 >> 10;             // 0=Q 1=K 2=V (block-uniform; 128|1024)
    const int nl     = n0 & 1023;

    const __hip_bfloat16* A = (region == 0) ? xb : yb;

    floatx4 acc[4][4];
#pragma unroll
    for (int i = 0; i < 4; ++i)
#pragma unroll
        for (int j = 0; j < 4; ++j) acc[i][j] = (floatx4){0.f, 0.f, 0.f, 0.f};

    auto stageA = [&](int h) {
        const int k0 = h * 32, slot = h % 3;
#pragma unroll
        for (int l = 0; l < 2; ++l) {
            const int c   = l * 512 + t;
            const int row = c >> 2;
            const int ch  = (c & 3) ^ ((row >> 1) & 3);
            async16(A + (size_t)(m0 + row) * Kd + k0 + ch * 8, &As[slot][c * 8]);
        }
    };
    auto stageB = [&](int h) {
        const int k0 = h * 32, slot = h % 3;
        const int c   = t;
        const int row = c >> 2;
        const int ch  = (c & 3) ^ ((row >> 1) & 3);
        async16(Bt + (size_t)(n0 + row) * Kd + k0 + ch * 8, &Bs[slot][c * 8]);
    };

    stageA(0); stageB(0); stageA(1); stageB(1);
    asm volatile("s_waitcnt vmcnt(3)" ::: "memory");
    __builtin_amdgcn_sched_barrier(0);
    __builtin_amdgcn_s_barrier();

    const int csw = (l16 >> 1) & 3;   // read-side chunk swizzle (== (row>>1)&3)

    for (int h = 0; h < NHS; ++h) {
        const int slot = h % 3;
        const __hip_bfloat16* as = &As[slot][0];
        const __hip_bfloat16* bs = &Bs[slot][0];
        short8 af[4], bf[4];

        // ---- phase A: bf[0..3] + af[0..1], stage A(h+2), 8 MFMA ----
#pragma unroll
        for (int nj = 0; nj < 4; ++nj) {
            const int row = wn * 64 + nj * 16 + l16;
            bf[nj] = *(const short8*)&bs[row * 32 + (quad ^ csw) * 8];
        }
#pragma unroll
        for (int mi = 0; mi < 2; ++mi) {
            const int row = wm * 64 + mi * 16 + l16;
            af[mi] = *(const short8*)&as[row * 32 + (quad ^ csw) * 8];
        }
        if (h + 2 < NHS) stageA(h + 2);
        __builtin_amdgcn_s_barrier();
        asm volatile("s_waitcnt lgkmcnt(0)" ::: "memory");
        __builtin_amdgcn_sched_barrier(0);
        __builtin_amdgcn_s_setprio(1);
#pragma unroll
        for (int mi = 0; mi < 2; ++mi)
#pragma unroll
            for (int nj = 0; nj < 4; ++nj)
                acc[mi][nj] = __builtin_amdgcn_mfma_f32_16x16x32_bf16(af[mi], bf[nj], acc[mi][nj], 0, 0, 0);
        __builtin_amdgcn_s_setprio(0);
        __builtin_amdgcn_s_barrier();

        // ---- phase B: af[2..3], stage B(h+2), 8 MFMA, counted vmcnt ----
#pragma unroll
        for (int mi = 2; mi < 4; ++mi) {
            const int row = wm * 64 + mi * 16 + l16;
            af[mi] = *(const short8*)&as[row * 32 + (quad ^ csw) * 8];
        }
        if (h + 2 < NHS) stageB(h + 2);
        __builtin_amdgcn_s_barrier();
        asm volatile("s_waitcnt lgkmcnt(0)" ::: "memory");
        __builtin_amdgcn_sched_barrier(0);
        __builtin_amdgcn_s_setprio(1);
#pragma unroll
        for (int mi = 2; mi < 4; ++mi)
#pragma unroll
            for (int nj = 0; nj < 4; ++nj)
                acc[mi][nj] = __builtin_amdgcn_mfma_f32_16x16x32_bf16(af[mi], bf[nj], acc[mi][nj], 0, 0, 0);
        __builtin_amdgcn_s_setprio(0);
        if (h + 2 < NHS)      asm volatile("s_waitcnt vmcnt(3)" ::: "memory");
        else                  asm volatile("s_waitcnt vmcnt(0)" ::: "memory");
        __builtin_amdgcn_sched_barrier(0);
        __builtin_amdgcn_s_barrier();
    }

    if (region < 2) {
        __hip_bfloat16* C    = (region == 0) ? Qb : Kb;
        const float*    bias = (region == 0) ? bq : bk;
        const float     scl  = (region == 0) ? qscl : 1.0f;
#pragma unroll
        for (int j = 0; j < 4; ++j) {
            const int col = nl + wn * 64 + j * 16 + l16;
            const float bvv = bias[col];
#pragma unroll
            for (int mi = 0; mi < 4; ++mi) {
#pragma unroll
                for (int r = 0; r < 4; ++r) {
                    const int row = m0 + wm * 64 + mi * 16 + quad * 4 + r;
                    C[(size_t)row * 1024 + col] = __float2bfloat16((acc[mi][j][r] + bvv) * scl);
                }
            }
        }
    } else {
        // V transposed per head: addr = (b*1024 + col)*2048 + j.
#pragma unroll
        for (int j = 0; j < 4; ++j) {
            const int col = nl + wn * 64 + j * 16 + l16;
            const float bvv = bv[col];
#pragma unroll
            for (int mi = 0; mi < 4; ++mi) {
                const int row0 = m0 + wm * 64 + mi * 16 + quad * 4;
                union { __hip_bfloat16 h4[4]; uint2 u; } pk;
#pragma unroll
                for (int r = 0; r < 4; ++r)
                    pk.h4[r] = __float2bfloat16(acc[mi][j][r] + bvv);
                *(uint2*)&Vt[((size_t)((row0 >> 11) * 1024 + col)) * 2048 + (row0 & 2047)] = pk.u;
            }
        }
    }
}

// ---------------------------------------------------------------------------
// O-projection GEMM: 64x128 tile, XCD-rect, f32 out; 3-buffer depth-2
// counted-vmcnt pipeline (3 async16/stage -> vmcnt(3|0)).
// ---------------------------------------------------------------------------
__global__ __launch_bounds__(256) void gemm_o(
    const __hip_bfloat16* __restrict__ A,    // [M,1024]
    const __hip_bfloat16* __restrict__ Bt,   // [1024,1024] (Wot)
    const float* __restrict__ bias,
    float* __restrict__ C,                   // [M,1024] f32
    int M)
{
    constexpr int BM = 64, BN = 128, BK = 32, Kd = 1024, NIT = Kd / BK;
    __shared__ __align__(16) __hip_bfloat16 As[3][BM * BK];  // 3 x 4 KB
    __shared__ __align__(16) __hip_bfloat16 Bs[3][BN * BK];  // 3 x 8 KB

    const int t    = threadIdx.x;
    const int w    = t >> 6;
    const int lane = t & 63;
    const int quad = lane >> 4;
    const int l16  = lane & 15;
    const int wm   = w & 1;         // 2 m-halves of 32 rows
    const int wn   = w >> 1;        // 2 n-halves of 64 cols

    // XCD-rect decode: 512 = 8 XCD x (4bx x 16by)
    const int f  = blockIdx.x;
    const int rx = f & 7;
    const int rr = f >> 3;               // 0..63
    const int bx = (rx & 1) * 4 + (rr & 3);
    const int by = (rx >> 1) * 16 + (rr >> 2);
    const int m0 = by * BM;
    const int n0 = bx * BN;

    const int lrow = lane >> 2;
    const int lcol = (lane & 3) * 8;

    floatx4 acc[2][4];
#pragma unroll
    for (int i = 0; i < 2; ++i)
#pragma unroll
        for (int j = 0; j < 4; ++j) acc[i][j] = (floatx4){0.f, 0.f, 0.f, 0.f};

    // 12 segments (4 A + 8 B), 3 per wave
    auto stage = [&](int k0, int buf) {
#pragma unroll
        for (int s = 0; s < 3; ++s) {
            const int seg = w * 3 + s;
            if (seg < 4) {
                async16(A + (size_t)(m0 + seg * 16 + lrow) * Kd + k0 + lcol,
                        &As[buf][seg * 16 * BK]);
            } else {
                const int bs = seg - 4;
                async16(Bt + (size_t)(n0 + bs * 16 + lrow) * Kd + k0 + lcol,
                        &Bs[buf][bs * 16 * BK]);
            }
        }
    };

    stage(0, 0);
    stage(BK, 1);
    int cur = 0;
    for (int i = 0; i < NIT; ++i) {
        if (i < NIT - 1) asm volatile("s_waitcnt vmcnt(3)" ::: "memory");
        else             asm volatile("s_waitcnt vmcnt(0)" ::: "memory");
        __builtin_amdgcn_sched_barrier(0);
        __builtin_amdgcn_s_barrier();
        if (i + 2 < NIT) stage((i + 2) * BK, (cur + 2 >= 3) ? cur - 1 : cur + 2);

        short8 af[2], bf[4];
#pragma unroll
        for (int ii = 0; ii < 2; ++ii)
            af[ii] = *(const short8*)&As[cur][(wm * 32 + ii * 16 + l16) * BK + quad * 8];
#pragma unroll
        for (int j = 0; j < 4; ++j)
            bf[j] = *(const short8*)&Bs[cur][(wn * 64 + j * 16 + l16) * BK + quad * 8];
#pragma unroll
        for (int ii = 0; ii < 2; ++ii)
#pragma unroll
            for (int j = 0; j < 4; ++j)
                acc[ii][j] = __builtin_amdgcn_mfma_f32_16x16x32_bf16(af[ii], bf[j], acc[ii][j], 0, 0, 0);
        cur = (cur + 1 >= 3) ? 0 : cur + 1;
    }

#pragma unroll
    for (int j = 0; j < 4; ++j) {
        const int col = n0 + wn * 64 + j * 16 + l16;
        const float bvf = bias[col];
#pragma unroll
        for (int i = 0; i < 2; ++i) {
#pragma unroll
            for (int r = 0; r < 4; ++r) {
                const int row = m0 + wm * 32 + i * 16 + quad * 4 + r;
                C[(size_t)row * 1024 + col] = acc[i][j][r] + bvf;
            }
        }
    }
}

// ---------------------------------------------------------------------------
// Fallback GEMM (fp32 inputs, fused convert, 64x64 tile). TRANSV writes the
// output per-head-transposed into Vt layout.
// ---------------------------------------------------------------------------
template <bool A_IS_F32, bool OUT_F32, bool TRANSV = false>
__global__ __launch_bounds__(256) void gemm64(
    const void* __restrict__ Av,
    const float* __restrict__ B,
    const float* __restrict__ bias,
    void* __restrict__ Cv,
    int M, int N, int K, float scale)
{
    __shared__ __align__(16) __hip_bfloat16 As[64][40];
    __shared__ __align__(16) __hip_bfloat16 Bs[64][40];

    const int t    = threadIdx.x;
    const int wave = t >> 6;
    const int lane = t & 63;
    const int quad = lane >> 4;
    const int l16  = lane & 15;
    const int m0   = blockIdx.y * 64;
    const int n0   = blockIdx.x * 64;

    floatx4 acc[4];
#pragma unroll
    for (int i = 0; i < 4; ++i) acc[i] = (floatx4){0.f, 0.f, 0.f, 0.f};

    const int arow = t >> 2, acol = (t & 3) * 8;
    const int bkk  = t >> 3, bnn  = (t & 7) * 8;

    for (int k0 = 0; k0 < K; k0 += 32) {
        if constexpr (A_IS_F32) {
            const float* A = (const float*)Av;
            const float* ap = A + (size_t)(m0 + arow) * K + k0 + acol;
            float4 a0 = ((const float4*)ap)[0];
            float4 a1 = ((const float4*)ap)[1];
            union { __hip_bfloat16 h[8]; short8 s; } up;
            up.h[0] = __float2bfloat16(a0.x); up.h[1] = __float2bfloat16(a0.y);
            up.h[2] = __float2bfloat16(a0.z); up.h[3] = __float2bfloat16(a0.w);
            up.h[4] = __float2bfloat16(a1.x); up.h[5] = __float2bfloat16(a1.y);
            up.h[6] = __float2bfloat16(a1.z); up.h[7] = __float2bfloat16(a1.w);
            *(short8*)(&As[arow][acol]) = up.s;
        } else {
            const __hip_bfloat16* A = (const __hip_bfloat16*)Av;
            uint4 av = *(const uint4*)(A + (size_t)(m0 + arow) * K + k0 + acol);
            *(uint4*)(&As[arow][acol]) = av;
        }
        {
            const float* bp = B + (size_t)(k0 + bkk) * N + n0 + bnn;
            float4 b0 = ((const float4*)bp)[0];
            float4 b1 = ((const float4*)bp)[1];
            Bs[bnn + 0][bkk] = __float2bfloat16(b0.x);
            Bs[bnn + 1][bkk] = __float2bfloat16(b0.y);
            Bs[bnn + 2][bkk] = __float2bfloat16(b0.z);
            Bs[bnn + 3][bkk] = __float2bfloat16(b0.w);
            Bs[bnn + 4][bkk] = __float2bfloat16(b1.x);
            Bs[bnn + 5][bkk] = __float2bfloat16(b1.y);
            Bs[bnn + 6][bkk] = __float2bfloat16(b1.z);
            Bs[bnn + 7][bkk] = __float2bfloat16(b1.w);
        }
        __syncthreads();

        short8 afrag = *(const short8*)(&As[wave * 16 + l16][quad * 8]);
#pragma unroll
        for (int nt = 0; nt < 4; ++nt) {
            short8 bfrag = *(const short8*)(&Bs[nt * 16 + l16][quad * 8]);
            acc[nt] = __builtin_amdgcn_mfma_f32_16x16x32_bf16(afrag, bfrag, acc[nt], 0, 0, 0);
        }
        __syncthreads();
    }

#pragma unroll
    for (int nt = 0; nt < 4; ++nt) {
        const int col = n0 + nt * 16 + l16;
        const float bvf = bias[col];
        if constexpr (TRANSV) {
            const int row0 = m0 + wave * 16 + quad * 4;
            union { __hip_bfloat16 h4[4]; uint2 u; } pk;
#pragma unroll
            for (int r = 0; r < 4; ++r)
                pk.h4[r] = __float2bfloat16(acc[nt][r] + bvf);
            *(uint2*)&((__hip_bfloat16*)Cv)[((size_t)((row0 >> 11) * 1024 + col)) * 2048 + (row0 & 2047)] = pk.u;
        } else {
#pragma unroll
            for (int r = 0; r < 4; ++r) {
                const int row = m0 + wave * 16 + quad * 4 + r;
                const float v = (acc[nt][r] + bvf) * scale;
                if constexpr (OUT_F32) ((float*)Cv)[(size_t)row * N + col] = v;
                else ((__hip_bfloat16*)Cv)[(size_t)row * N + col] = __float2bfloat16(v);
            }
        }
    }
}

// ---------------------------------------------------------------------------
// MFMA flash attention v12 = v11 with 512 threads / 8 waves x 16 q rows:
// guarantees 2 waves/SIMD from ONE block (the balance-paired partner often
// dies early, leaving 1 wave/SIMD in v11 -- Occupancy 11% evidence). Waves'
// per-tile chains interleave between barriers. T15 2-tile pipeline, 3 K / 4 V
// slots, counted vmcnt (2 loads/thread/stage -> vmcnt(2)), race-safe
// post-barrier staging, XCD clustering + causal balance pairing unchanged.
// ---------------------------------------------------------------------------
#define PP 72                 // P/Q row pitch (144 B = 9*16B, aligned)

__global__ __launch_bounds__(512, 4) void attn_mfma12(
    const __hip_bfloat16* __restrict__ Q,
    const __hip_bfloat16* __restrict__ K,
    const __hip_bfloat16* __restrict__ Vt,   // [b][h][64 d][2048 j]
    __hip_bfloat16* __restrict__ O)
{
    __shared__ __align__(16) __hip_bfloat16 KtS[3][64 * 64];  // 24 KB, swizzled rows
    __shared__ __align__(16) __hip_bfloat16 VtS[4][64 * 64];  // 32 KB, swizzled rows
    __shared__ __align__(16) __hip_bfloat16 PsQ[128 * PP];    // 18 KB: Q stage, then per-wave P

    const int t    = threadIdx.x;
    const int w    = t >> 6;        // 0..7
    const int lane = t & 63;
    const int quad = lane >> 4;
    const int l16  = lane & 15;

    // XCD-clustered + balance-paired decode
    const int f   = blockIdx.x;
    const int xcd = f & 7;
    const int u   = f >> 3;        // 0..63
    const int pi  = u >> 4;        // 0..3 (pair index within XCD)
    const int qr  = u & 15;
    const int qx  = (pi & 2) ? (15 - qr) : qr;   // second round flips -> 34 iters/CU
    const int p   = xcd * 4 + pi;  // (b,h) pair 0..31
    const int h   = p & 15;
    const int b   = p >> 4;
    const int q0  = qx * 128;

    const size_t rowbase = (size_t)b * LQ;
    const int    hcol    = h * 64;
    const size_t vbase   = (size_t)(b * NH + h) * 64 * LQ;

    const int r8 = l16 & 7;

    // stage K (slot jt%3) and V^T (slot jt&3) 64x64 tiles; pre-swizzled
    // global source, linear LDS dest. 512 thr -> 1 chunk each: 2 async16/thr.
    auto stage = [&](int j0n, int jtile) {
        const int ks = jtile % 3;
        const int vs = jtile & 3;
        const int c   = t;                      // 16B chunk index, 0..511
        const int row = c >> 3;                 // 0..63
        const int ch  = (c & 7) ^ (row & 7);    // swizzled source chunk
        async16(K + (rowbase + j0n + row) * DM + hcol + ch * 8,
                &KtS[ks][c * 8]);
        async16(Vt + vbase + (size_t)row * LQ + j0n + ch * 8,
                &VtS[vs][c * 8]);
    };

    // ---- Q tile (128 rows x 64) -> LDS; t>>2 keeps rows wave-local ----
    {
        const int qrow = t >> 2, qseg = (t & 3) * 16;   // 32B per thread
        const uint4* src = (const uint4*)(Q + (rowbase + q0 + qrow) * DM + hcol + qseg);
        uint4* dst = (uint4*)&PsQ[qrow * PP + qseg];
        dst[0] = src[0]; dst[1] = src[1];
    }
    stage(0, 0);
    stage(64, 1);

    // qf reads own wave's rows (ordered vs own stores by lgkmcnt)
    short8 qf[2];
#pragma unroll
    for (int hh = 0; hh < 2; ++hh)
        qf[hh] = *(const short8*)&PsQ[(w * 16 + l16) * PP + hh * 32 + quad * 8];

    __hip_bfloat16* Pw = &PsQ[(w * 16) * PP];  // wave-private P[16 q][64 j]

    float l_i = 0.f;
    floatx4 o[4];
#pragma unroll
    for (int i = 0; i < 4; ++i) o[i] = (floatx4){0.f, 0.f, 0.f, 0.f};

    const int wq_lo  = q0 + w * 16;       // first q row of this wave
    const int wq_hi  = wq_lo + 15;
    const int ntiles = 2 * qx + 2;

    short8 pa[2];             // P fragments of the PREVIOUS tile (persist)
    int    pslot = -1;        // V slot of the previous tile; -1 = none

    for (int jt = 0; jt < ntiles; ++jt) {
        const int j0 = jt * 64;

        // retire own stage(jt) (2 loads), keep stage(jt+1) in flight
        if (jt < ntiles - 1) asm volatile("s_waitcnt vmcnt(2)" ::: "memory");
        else                 asm volatile("s_waitcnt vmcnt(0)" ::: "memory");
        __builtin_amdgcn_sched_barrier(0);
        __builtin_amdgcn_s_barrier();
        // safe: K slot (jt+2)%3 and V slot (jt+2)&3 retired by the barrier
        if (jt + 2 < ntiles) stage(j0 + 128, jt + 2);

        const bool active = (j0 <= wq_hi);

        // ---- issue K(jt) fragment reads early (overlap with PV below) ----
        short8 ak[4][2];
        if (active) {
#pragma unroll
            for (int jc = 0; jc < 4; ++jc) {
                const __hip_bfloat16* kr = &KtS[jt % 3][(jc * 16 + l16) * 64];
                ak[jc][0] = *(const short8*)&kr[((quad    ) ^ r8) * 8];
                ak[jc][1] = *(const short8*)&kr[((quad + 4) ^ r8) * 8];
            }
        }

        // ---- PV of PREVIOUS tile (pure MFMA; hides K ds_read latency) ----
        if (pslot >= 0) {
            __builtin_amdgcn_s_setprio(1);
#pragma unroll
            for (int subf = 0; subf < 4; ++subf) {
                const __hip_bfloat16* vr = &VtS[pslot][(subf * 16 + l16) * 64];
                short8 vb0 = *(const short8*)&vr[((quad    ) ^ r8) * 8];
                short8 vb1 = *(const short8*)&vr[((quad + 4) ^ r8) * 8];
                o[subf] = __builtin_amdgcn_mfma_f32_16x16x32_bf16(pa[0], vb0, o[subf], 0, 0, 0);
                o[subf] = __builtin_amdgcn_mfma_f32_16x16x32_bf16(pa[1], vb1, o[subf], 0, 0, 0);
            }
            __builtin_amdgcn_s_setprio(0);
            pslot = -1;
        }

        if (active) {
            const bool bnd = (j0 + 63 > wq_lo);   // boundary: needs causal mask
            // ---- S^T = K * Q^T, fused softmax numerator per jc ----
            __builtin_amdgcn_s_setprio(1);
#pragma unroll
            for (int jc = 0; jc < 4; ++jc) {
                floatx4 z = (floatx4){0.f, 0.f, 0.f, 0.f};
                z = __builtin_amdgcn_mfma_f32_16x16x32_bf16(ak[jc][0], qf[0], z, 0, 0, 0);
                z = __builtin_amdgcn_mfma_f32_16x16x32_bf16(ak[jc][1], qf[1], z, 0, 0, 0);
                if (bnd) {
                    const int qg = wq_lo + l16;
#pragma unroll
                    for (int r = 0; r < 4; ++r) {
                        const int j = j0 + jc * 16 + quad * 4 + r;
                        if (j > qg) z[r] = -1e30f;
                    }
                }
                union { __hip_bfloat16 h4[4]; uint2 u; } pk;
#pragma unroll
                for (int r = 0; r < 4; ++r) {
                    const float e = __builtin_amdgcn_exp2f(z[r]);
                    l_i += e;
                    pk.h4[r] = __float2bfloat16(e);
                }
                *(uint2*)&Pw[l16 * PP + jc * 16 + quad * 4] = pk.u;
            }
            __builtin_amdgcn_s_setprio(0);
            // ---- P frags for NEXT iter's PV (wave-local write->read) ----
            pa[0] = *(const short8*)&Pw[l16 * PP + quad * 8];
            pa[1] = *(const short8*)&Pw[l16 * PP + 32 + quad * 8];
            pslot = jt & 3;
        }
    }

    // ---- flush final PV (V slot of the last active tile is not reused) ----
    if (pslot >= 0) {
#pragma unroll
        for (int subf = 0; subf < 4; ++subf) {
            const __hip_bfloat16* vr = &VtS[pslot][(subf * 16 + l16) * 64];
            short8 vb0 = *(const short8*)&vr[((quad    ) ^ r8) * 8];
            short8 vb1 = *(const short8*)&vr[((quad + 4) ^ r8) * 8];
            o[subf] = __builtin_amdgcn_mfma_f32_16x16x32_bf16(pa[0], vb0, o[subf], 0, 0, 0);
            o[subf] = __builtin_amdgcn_mfma_f32_16x16x32_bf16(pa[1], vb1, o[subf], 0, 0, 0);
        }
    }

    l_i += __shfl_xor(l_i, 16);
    l_i += __shfl_xor(l_i, 32);
#pragma unroll
    for (int r = 0; r < 4; ++r) {
        const float linv = 1.0f / __shfl(l_i, quad * 4 + r);
        const size_t row = rowbase + q0 + w * 16 + quad * 4 + r;
#pragma unroll
        for (int subf = 0; subf < 4; ++subf)
            O[row * DM + hcol + subf * 16 + l16] = __float2bfloat16(o[subf][r] * linv);
    }
}

// ---------------------------------------------------------------------------
extern "C" void kernel_launch(void* const* d_in, const int* in_sizes, int n_in,
                              void* d_out, int out_size, void* d_ws, size_t ws_size,
                              hipStream_t stream)
{
    (void)in_sizes; (void)n_in; (void)out_size;

    const float* x  = (const float*)d_in[0];
    const float* y  = (const float*)d_in[1];
    // d_in[2] = mask: causal tril, handled analytically
    const float* Wq = (const float*)d_in[3];
    const float* bq = (const float*)d_in[4];
    const float* Wk = (const float*)d_in[5];
    const float* bk = (const float*)d_in[6];
    const float* Wv = (const float*)d_in[7];
    const float* bv = (const float*)d_in[8];
    const float* Wo = (const float*)d_in[9];
    const float* bo = (const float*)d_in[10];

    const size_t NTOK = (size_t)2 * LQ * DM;   // 4,194,304
    const size_t MM   = (size_t)DM * DM;       // 1,048,576
    const int    M    = 2 * LQ;                // 4096
    const float  QSCL = 0.125f * LOG2E;        // 1/sqrt(dk) * log2(e): exp2-domain softmax

    __hip_bfloat16* Qb  = (__hip_bfloat16*)d_ws;
    __hip_bfloat16* Kb  = Qb + NTOK;
    __hip_bfloat16* Vtb = Kb + NTOK;           // transposed V: [b][h][64][2048]
    __hip_bfloat16* Ab  = Vtb + NTOK;

    const size_t need = (4 * NTOK + 2 * NTOK + 4 * MM) * sizeof(__hip_bfloat16);
    const dim3 agrid(512, 1, 1);  // flat, XCD-clustered decode in-kernel

    if (ws_size >= need) {
        __hip_bfloat16* xb  = Ab + NTOK;
        __hip_bfloat16* yb  = xb + NTOK;
        __hip_bfloat16* Wqt = yb + NTOK;
        __hip_bfloat16* Wkt = Wqt + MM;   // [Wqt; Wkt; Wvt] contiguous = stacked QKV B
        __hip_bfloat16* Wvt = Wkt + MM;
        __hip_bfloat16* Wot = Wvt + MM;
        (void)Wkt; (void)Wvt;

        prep_all<<<5120, 256, 0, stream>>>(x, y, Wq, Wk, Wv, Wo,
                                           xb, yb, Wqt, Wkt, Wvt, Wot);

        gemm_qkv<<<384, 512, 0, stream>>>(xb, yb, Wqt, bq, bk, bv, Qb, Kb, Vtb, QSCL);
        attn_mfma12<<<agrid, 512, 0, stream>>>(Qb, Kb, Vtb, Ab);
        gemm_o<<<512, 256, 0, stream>>>(Ab, Wot, bo, (float*)d_out, M);
    } else {
        const dim3 gblk(DM / 64, M / 64);
        gemm64<true,  false><<<gblk, 256, 0, stream>>>(x, Wq, bq, Qb, M, DM, DM, QSCL);
        gemm64<true,  false><<<gblk, 256, 0, stream>>>(y, Wk, bk, Kb, M, DM, DM, 1.0f);
        gemm64<true,  false, true><<<gblk, 256, 0, stream>>>(y, Wv, bv, Vtb, M, DM, DM, 1.0f);
        attn_mfma12<<<agrid, 512, 0, stream>>>(Qb, Kb, Vtb, Ab);
        gemm64<false, true ><<<gblk, 256, 0, stream>>>(Ab, Wo, bo, (float*)d_out, M, DM, DM, 1.0f);
    }
}